// Round 3
// baseline (253.613 us; speedup 1.0000x reference)
//
#include <hip/hip_runtime.h>
#include <math.h>

// Problem constants (from reference): B=8, N=2048, C_IN=3, D=64, K=8, LEVELS=3, H1=256, H2=128
#define BB   8
#define NN   2048
#define BN   16384   // B*N
#define DD   64
#define KNB  8
#define H1D  256
#define H2D  128

__device__ __forceinline__ float leaky(float v){ return v > 0.f ? v : 0.2f*v; }

// ---------------------------------------------------------------------------
// K1: per-point feature transform + suppressor weights.
// wave per point, lane = feature dim d (64).
// ---------------------------------------------------------------------------
__global__ __launch_bounds__(256) void k_feat_fw(
    const float* __restrict__ x,
    const float* __restrict__ W1, const float* __restrict__ b1,
    const float* __restrict__ g1, const float* __restrict__ be1,
    const float* __restrict__ Ws1, const float* __restrict__ bs1,
    const float* __restrict__ Ws2, const float* __restrict__ bs2,
    float* __restrict__ feat, float* __restrict__ fw)
{
    int lane = threadIdx.x & 63;
    int p = blockIdx.x * 4 + (threadIdx.x >> 6);
    float x0 = x[p*3+0], x1 = x[p*3+1], x2 = x[p*3+2];
    int d = lane;

    float f = x0*W1[d] + x1*W1[64+d] + x2*W1[128+d] + b1[d];
    f = leaky(f * g1[d] + be1[d]);
    feat[p*64 + d] = f;

    float h = x0*Ws1[d] + x1*Ws1[64+d] + x2*Ws1[128+d] + bs1[d];
    h = fmaxf(h, 0.f);
    float s[3];
    #pragma unroll
    for (int l = 0; l < 3; ++l) {
        float v = h * Ws2[d*3 + l];
        #pragma unroll
        for (int off = 32; off; off >>= 1) v += __shfl_xor(v, off, 64);
        s[l] = v;
    }
    if (lane < 3) fw[p*3 + lane] = 1.f / (1.f + expf(-(s[lane] + bs2[lane])));
}

// ---------------------------------------------------------------------------
// K2: exact KNN, top-8 smallest d2, ties -> lower index (== stable top_k).
// Key trick: (d2,index) packed into u64 (hi = order-preserving transform of
// d2 bits, lo = local index). One v_cmp_lt_u64 per bubble level.
// Block: 1024 thr = 32 queries x 32 segments x 64 candidates.
// Grid 512 -> 2 blocks/CU, 32 waves/CU (100% nominal occupancy).
// Merge: log-tree of register bitonic merges, SoA LDS (conflict-free).
// ---------------------------------------------------------------------------
#define CE64(a, b) { bool c_ = (b) < (a); unsigned long long mn_ = c_ ? (b) : (a); \
                     unsigned long long mx_ = c_ ? (a) : (b); (a) = mn_; (b) = mx_; }

__global__ __launch_bounds__(1024, 8) void k_knn(const float* __restrict__ x, int* __restrict__ idxo)
{
    __shared__ __align__(16) char smem[65536];
    float4*   sp  = (float4*)smem;               // 2048*16 = 32 KB (scan phase)
    unsigned* khi = (unsigned*)smem;             // [8][1024]  32 KB (merge phase)
    unsigned* klo = (unsigned*)(smem + 32768);   // [8][1024]  32 KB

    int t = threadIdx.x;
    int b = blockIdx.x >> 6;
    int qbase = (blockIdx.x & 63) * 32;
    int q = t & 31, seg = t >> 5;

    for (int i = t; i < NN; i += 1024) {
        float a = x[(b*NN + i)*3 + 0];
        float c = x[(b*NN + i)*3 + 1];
        float e = x[(b*NN + i)*3 + 2];
        sp[i] = make_float4(a, c, e, a*a + c*c + e*e);
    }
    __syncthreads();

    float4 qv = sp[qbase + q];

    unsigned long long bk[8];
    #pragma unroll
    for (int j = 0; j < 8; ++j) bk[j] = 0xFFFFFFFFFFFFFFFFull;

    int m0 = seg * 64;
    #pragma unroll 8
    for (int jj = 0; jj < 64; ++jj) {
        int m = m0 + jj;
        float4 v = sp[m];
        float s = qv.x*v.x; s = fmaf(qv.y, v.y, s); s = fmaf(qv.z, v.z, s);
        float d2 = fmaf(-2.f, s, qv.w + v.w);
        // order-preserving float->uint map (handles tiny negative d2 from fp cancellation)
        unsigned ub = __float_as_uint(d2);
        unsigned u  = ub ^ (unsigned)(((int)ub >> 31) | 0x80000000);
        unsigned long long ck = ((unsigned long long)u << 32) | (unsigned)m;
        #pragma unroll
        for (int j = 0; j < 8; ++j) {
            bool c = ck < bk[j];
            unsigned long long mn = c ? ck : bk[j];
            unsigned long long mx = c ? bk[j] : ck;
            bk[j] = mn; ck = mx;
        }
    }

    __syncthreads();   // all sp reads done; overlay
    // column-major store: list 'seg' of query q lives at row seg*32+q == t
    #pragma unroll
    for (int j = 0; j < 8; ++j) {
        khi[j*1024 + t] = (unsigned)(bk[j] >> 32);
        klo[j*1024 + t] = (unsigned)bk[j];
    }

    // tree merge: L lists -> L/2, lists block-ordered by index so u64 compare
    // remains globally stable
    for (int L = 32; L >= 2; L >>= 1) {
        __syncthreads();
        unsigned long long A[8], Bv[8];
        int p = t >> 5;
        bool active = (p < (L >> 1));
        if (active) {
            int rowA = (2*p)*32 + q, rowB = (2*p + 1)*32 + q;
            #pragma unroll
            for (int j = 0; j < 8; ++j) {
                A[j]  = ((unsigned long long)khi[j*1024 + rowA] << 32) | klo[j*1024 + rowA];
                Bv[j] = ((unsigned long long)khi[j*1024 + rowB] << 32) | klo[j*1024 + rowB];
            }
        }
        __syncthreads();
        if (active) {
            unsigned long long C[8];
            #pragma unroll
            for (int j = 0; j < 8; ++j) {
                unsigned long long bb = Bv[7-j];
                C[j] = A[j] < bb ? A[j] : bb;    // 8 smallest of union, bitonic seq
            }
            CE64(C[0],C[4]); CE64(C[1],C[5]); CE64(C[2],C[6]); CE64(C[3],C[7]);
            CE64(C[0],C[2]); CE64(C[1],C[3]); CE64(C[4],C[6]); CE64(C[5],C[7]);
            CE64(C[0],C[1]); CE64(C[2],C[3]); CE64(C[4],C[5]); CE64(C[6],C[7]);
            if (L > 2) {
                int rowO = p*32 + q;
                #pragma unroll
                for (int j = 0; j < 8; ++j) {
                    khi[j*1024 + rowO] = (unsigned)(C[j] >> 32);
                    klo[j*1024 + rowO] = (unsigned)C[j];
                }
            } else {
                #pragma unroll
                for (int j = 0; j < 8; ++j)
                    idxo[(b*NN + qbase + q)*KNB + j] = b*NN + (int)(C[j] & 0xFFFFFFFFu);
            }
        }
    }
}

// ---------------------------------------------------------------------------
// Generic fp32 tiled GEMM: C[M,*] (ldc) = epilogue(A[M,K] @ W[K,*] (ldw)).
// Tile 128x64, 256 threads, 4x8 micro-tile, BK=32.
// ---------------------------------------------------------------------------
__global__ __launch_bounds__(256) void k_gemm(
    const float* __restrict__ A, const float* __restrict__ W, float* __restrict__ C,
    int K, int ldw, int ldc,
    const float* __restrict__ bias, const float* __restrict__ gam,
    const float* __restrict__ bet, int act)
{
    __shared__ float A_s[128*36];   // 18 KB
    __shared__ float W_s[32*64];    // 8 KB

    int t  = threadIdx.x;
    int tx = t & 7;        // col group: 8 cols
    int ty = t >> 3;       // row group: 4 rows
    int rb = blockIdx.x * 128;
    int cb = blockIdx.y * 64;

    float acc[4][8];
    #pragma unroll
    for (int i = 0; i < 4; ++i)
        #pragma unroll
        for (int j = 0; j < 8; ++j) acc[i][j] = 0.f;

    for (int k0 = 0; k0 < K; k0 += 32) {
        #pragma unroll
        for (int it = 0; it < 4; ++it) {
            int i = t + it*256;            // 0..1023
            int r = i >> 3, kq = (i & 7) * 4;
            float4 v = *(const float4*)&A[(rb + r)*K + k0 + kq];
            *(float4*)&A_s[r*36 + kq] = v;
        }
        #pragma unroll
        for (int it = 0; it < 2; ++it) {
            int i = t + it*256;            // 0..511
            int k = i >> 4, cq = (i & 15) * 4;
            float4 v = *(const float4*)&W[(k0 + k)*ldw + cb + cq];
            *(float4*)&W_s[k*64 + cq] = v;
        }
        __syncthreads();

        #pragma unroll
        for (int kk = 0; kk < 32; kk += 2) {
            float2 a[4];
            #pragma unroll
            for (int i = 0; i < 4; ++i) a[i] = *(const float2*)&A_s[(ty*4 + i)*36 + kk];
            float4 w00 = *(const float4*)&W_s[ kk   *64 + tx*8];
            float4 w01 = *(const float4*)&W_s[ kk   *64 + tx*8 + 4];
            float4 w10 = *(const float4*)&W_s[(kk+1)*64 + tx*8];
            float4 w11 = *(const float4*)&W_s[(kk+1)*64 + tx*8 + 4];
            #pragma unroll
            for (int i = 0; i < 4; ++i) {
                float ax = a[i].x, ay = a[i].y;
                acc[i][0] = fmaf(ax, w00.x, acc[i][0]);
                acc[i][1] = fmaf(ax, w00.y, acc[i][1]);
                acc[i][2] = fmaf(ax, w00.z, acc[i][2]);
                acc[i][3] = fmaf(ax, w00.w, acc[i][3]);
                acc[i][4] = fmaf(ax, w01.x, acc[i][4]);
                acc[i][5] = fmaf(ax, w01.y, acc[i][5]);
                acc[i][6] = fmaf(ax, w01.z, acc[i][6]);
                acc[i][7] = fmaf(ax, w01.w, acc[i][7]);
                acc[i][0] = fmaf(ay, w10.x, acc[i][0]);
                acc[i][1] = fmaf(ay, w10.y, acc[i][1]);
                acc[i][2] = fmaf(ay, w10.z, acc[i][2]);
                acc[i][3] = fmaf(ay, w10.w, acc[i][3]);
                acc[i][4] = fmaf(ay, w11.x, acc[i][4]);
                acc[i][5] = fmaf(ay, w11.y, acc[i][5]);
                acc[i][6] = fmaf(ay, w11.z, acc[i][6]);
                acc[i][7] = fmaf(ay, w11.w, acc[i][7]);
            }
        }
        __syncthreads();
    }

    #pragma unroll
    for (int i = 0; i < 4; ++i) {
        int r = rb + ty*4 + i;
        int cbase = cb + tx*8;
        float vo[8];
        #pragma unroll
        for (int j = 0; j < 8; ++j) {
            int c = cbase + j;
            float v = acc[i][j];
            if (bias) v += bias[c];
            if (gam)  v = v * gam[c] + bet[c];
            if (act)  v = leaky(v);
            vo[j] = v;
        }
        *(float4*)&C[r*ldc + cbase]     = make_float4(vo[0], vo[1], vo[2], vo[3]);
        *(float4*)&C[r*ldc + cbase + 4] = make_float4(vo[4], vo[5], vo[6], vo[7]);
    }
}

// ---------------------------------------------------------------------------
// K4: gather-max edge conv + frequency weighting.
// ---------------------------------------------------------------------------
__global__ __launch_bounds__(256) void k_agg_multi(
    const float* __restrict__ PQ, const int* __restrict__ idx,
    const float* __restrict__ fw,
    const float* __restrict__ b2, const float* __restrict__ g2, const float* __restrict__ be2,
    float* __restrict__ multi)
{
    int lane = threadIdx.x & 63;
    int p = blockIdx.x * 4 + (threadIdx.x >> 6);
    float Pv = PQ[p*128 + lane] + b2[lane];
    float g = g2[lane], be = be2[lane];
    float mx = -1e30f;
    #pragma unroll
    for (int j = 0; j < KNB; ++j) {
        int nb = idx[p*KNB + j];
        float v = (Pv + PQ[nb*128 + 64 + lane]) * g + be;
        mx = fmaxf(mx, leaky(v));
    }
    float w0 = fw[p*3+0], w1 = fw[p*3+1], w2 = fw[p*3+2];
    multi[p*192 + lane]        = mx * w0;
    multi[p*192 + 64  + lane]  = mx * w1;
    multi[p*192 + 128 + lane]  = mx * w2;
}

// ---------------------------------------------------------------------------
// K7: delta = h2 @ Wf3 + bf3 (128 -> 3); out = x + 0.1*delta. wave per point.
// ---------------------------------------------------------------------------
__global__ __launch_bounds__(256) void k_out(
    const float* __restrict__ h2, const float* __restrict__ Wf3, const float* __restrict__ bf3,
    const float* __restrict__ x, float* __restrict__ out)
{
    int lane = threadIdx.x & 63;
    int p = blockIdx.x * 4 + (threadIdx.x >> 6);
    float v0 = h2[p*128 + lane], v1 = h2[p*128 + 64 + lane];
    #pragma unroll
    for (int l = 0; l < 3; ++l) {
        float s = v0 * Wf3[lane*3 + l] + v1 * Wf3[(64 + lane)*3 + l];
        #pragma unroll
        for (int off = 32; off; off >>= 1) s += __shfl_xor(s, off, 64);
        if (lane == l) out[p*3 + l] = x[p*3 + l] + 0.1f*(s + bf3[l]);
    }
}

// ---------------------------------------------------------------------------
extern "C" void kernel_launch(void* const* d_in, const int* in_sizes, int n_in,
                              void* d_out, int out_size, void* d_ws, size_t ws_size,
                              hipStream_t stream)
{
    const float* x    = (const float*)d_in[0];
    const float* W1   = (const float*)d_in[1];
    const float* b1   = (const float*)d_in[2];
    const float* g1   = (const float*)d_in[3];
    const float* be1  = (const float*)d_in[4];
    const float* W2   = (const float*)d_in[5];
    const float* b2   = (const float*)d_in[6];
    const float* g2   = (const float*)d_in[7];
    const float* be2  = (const float*)d_in[8];
    const float* Ws1  = (const float*)d_in[9];
    const float* bs1  = (const float*)d_in[10];
    const float* Ws2  = (const float*)d_in[11];
    const float* bs2  = (const float*)d_in[12];
    const float* Wf1  = (const float*)d_in[13];
    const float* bf1  = (const float*)d_in[14];
    const float* gf1  = (const float*)d_in[15];
    const float* bef1 = (const float*)d_in[16];
    const float* Wf2  = (const float*)d_in[17];
    const float* bf2  = (const float*)d_in[18];
    const float* gf2  = (const float*)d_in[19];
    const float* bef2 = (const float*)d_in[20];
    const float* Wf3  = (const float*)d_in[21];
    const float* bf3  = (const float*)d_in[22];
    float* out = (float*)d_out;

    char* ws = (char*)d_ws;
    float* feat  = (float*)(ws + 0);                  // 4 MB   [BN,64]
    float* fw    = (float*)(ws + (4u  << 20));        // .75 MB [BN,3]
    int*   idx   = (int*)  (ws + (5u  << 20));        // .5 MB  [BN,8]
    float* PQ    = (float*)(ws + (6u  << 20));        // 8 MB   [BN,128]
    float* multi = (float*)(ws + (14u << 20));        // 12 MB  [BN,192]
    float* h1    = (float*)(ws + 0);                  // 16 MB  [BN,256] (feat/fw/idx/PQ dead)
    float* h2    = (float*)(ws + (16u << 20));        // 8 MB   [BN,128] (multi dead)

    k_feat_fw<<<BN/4, 256, 0, stream>>>(x, W1, b1, g1, be1, Ws1, bs1, Ws2, bs2, feat, fw);
    k_knn<<<BB*64, 1024, 0, stream>>>(x, idx);
    k_gemm<<<dim3(BN/128, 1), 256, 0, stream>>>(feat, W2,         PQ,      64, 64, 128,
                                                nullptr, nullptr, nullptr, 0);
    k_gemm<<<dim3(BN/128, 1), 256, 0, stream>>>(feat, W2 + 64*64, PQ + 64, 64, 64, 128,
                                                nullptr, nullptr, nullptr, 0);
    k_agg_multi<<<BN/4, 256, 0, stream>>>(PQ, idx, fw, b2, g2, be2, multi);
    k_gemm<<<dim3(BN/128, H1D/64), 256, 0, stream>>>(multi, Wf1, h1, 192, H1D, H1D,
                                                     bf1, gf1, bef1, 1);
    k_gemm<<<dim3(BN/128, H2D/64), 256, 0, stream>>>(h1, Wf2, h2, H1D, H2D, H2D,
                                                     bf2, gf2, bef2, 1);
    k_out<<<BN/4, 256, 0, stream>>>(h2, Wf3, bf3, x, out);
}

// Round 4
// 230.428 us; speedup vs baseline: 1.1006x; 1.1006x over previous
//
#include <hip/hip_runtime.h>
#include <math.h>

// Problem constants (from reference): B=8, N=2048, C_IN=3, D=64, K=8, LEVELS=3, H1=256, H2=128
#define BB   8
#define NN   2048
#define BN   16384   // B*N
#define DD   64
#define KNB  8
#define H1D  256
#define H2D  128

__device__ __forceinline__ float leaky(float v){ return v > 0.f ? v : 0.2f*v; }

// ---------------------------------------------------------------------------
// K1: per-point feature transform + suppressor weights.
// ---------------------------------------------------------------------------
__global__ __launch_bounds__(256) void k_feat_fw(
    const float* __restrict__ x,
    const float* __restrict__ W1, const float* __restrict__ b1,
    const float* __restrict__ g1, const float* __restrict__ be1,
    const float* __restrict__ Ws1, const float* __restrict__ bs1,
    const float* __restrict__ Ws2, const float* __restrict__ bs2,
    float* __restrict__ feat, float* __restrict__ fw)
{
    int lane = threadIdx.x & 63;
    int p = blockIdx.x * 4 + (threadIdx.x >> 6);
    float x0 = x[p*3+0], x1 = x[p*3+1], x2 = x[p*3+2];
    int d = lane;

    float f = x0*W1[d] + x1*W1[64+d] + x2*W1[128+d] + b1[d];
    f = leaky(f * g1[d] + be1[d]);
    feat[p*64 + d] = f;

    float h = x0*Ws1[d] + x1*Ws1[64+d] + x2*Ws1[128+d] + bs1[d];
    h = fmaxf(h, 0.f);
    float s[3];
    #pragma unroll
    for (int l = 0; l < 3; ++l) {
        float v = h * Ws2[d*3 + l];
        #pragma unroll
        for (int off = 32; off; off >>= 1) v += __shfl_xor(v, off, 64);
        s[l] = v;
    }
    if (lane < 3) fw[p*3 + lane] = 1.f / (1.f + expf(-(s[lane] + bs2[lane])));
}

// ---------------------------------------------------------------------------
// K2: exact KNN, top-8 smallest d2, ties -> lower index (== stable top_k).
// (d2,index) packed into u64 key (hi = order-preserving map of d2 bits).
// Scan processes candidates in groups of 8: Batcher sort-8 network (19 CE)
// + bitonic min-merge with running top-8 (8 min + 12 CE) — ~32 inst/cand
// vs ~107 for the per-candidate serial bubble (R3 measured).
// Block: 1024 thr = 32 queries x 32 segments x 64 candidates.
// ---------------------------------------------------------------------------
#define CE64(a, b) { bool c_ = (b) < (a); unsigned long long mn_ = c_ ? (b) : (a); \
                     unsigned long long mx_ = c_ ? (a) : (b); (a) = mn_; (b) = mx_; }

__global__ __launch_bounds__(1024, 8) void k_knn(const float* __restrict__ x, int* __restrict__ idxo)
{
    __shared__ __align__(16) char smem[65536];
    float4*   sp  = (float4*)smem;               // 2048*16 = 32 KB (scan phase)
    unsigned* khi = (unsigned*)smem;             // [8][1024]  32 KB (merge phase)
    unsigned* klo = (unsigned*)(smem + 32768);   // [8][1024]  32 KB

    int t = threadIdx.x;
    int b = blockIdx.x >> 6;
    int qbase = (blockIdx.x & 63) * 32;
    int q = t & 31, seg = t >> 5;

    for (int i = t; i < NN; i += 1024) {
        float a = x[(b*NN + i)*3 + 0];
        float c = x[(b*NN + i)*3 + 1];
        float e = x[(b*NN + i)*3 + 2];
        sp[i] = make_float4(a, c, e, a*a + c*c + e*e);
    }
    __syncthreads();

    float4 qv = sp[qbase + q];

    unsigned long long R[8];
    #pragma unroll
    for (int j = 0; j < 8; ++j) R[j] = 0xFFFFFFFFFFFFFFFFull;

    int m0 = seg * 64;
    #pragma unroll 2
    for (int g = 0; g < 8; ++g) {
        unsigned long long S[8];
        #pragma unroll
        for (int jj = 0; jj < 8; ++jj) {
            int m = m0 + g*8 + jj;
            float4 v = sp[m];
            float s = qv.x*v.x; s = fmaf(qv.y, v.y, s); s = fmaf(qv.z, v.z, s);
            float d2 = fmaf(-2.f, s, qv.w + v.w);
            unsigned ub = __float_as_uint(d2);
            unsigned u  = ub ^ (unsigned)(((int)ub >> 31) | 0x80000000);
            S[jj] = ((unsigned long long)u << 32) | (unsigned)m;
        }
        // Batcher odd-even mergesort, 8 elements, 19 CEs (ascending)
        CE64(S[0],S[1]); CE64(S[2],S[3]); CE64(S[4],S[5]); CE64(S[6],S[7]);
        CE64(S[0],S[2]); CE64(S[1],S[3]); CE64(S[4],S[6]); CE64(S[5],S[7]);
        CE64(S[1],S[2]); CE64(S[5],S[6]);
        CE64(S[0],S[4]); CE64(S[1],S[5]); CE64(S[2],S[6]); CE64(S[3],S[7]);
        CE64(S[2],S[4]); CE64(S[3],S[5]);
        CE64(S[1],S[2]); CE64(S[3],S[4]); CE64(S[5],S[6]);
        // keep 8 smallest of R ∪ S: min-phase then 3-stage bitonic cleanup
        #pragma unroll
        for (int j = 0; j < 8; ++j) {
            unsigned long long bb = S[7-j];
            R[j] = R[j] < bb ? R[j] : bb;
        }
        CE64(R[0],R[4]); CE64(R[1],R[5]); CE64(R[2],R[6]); CE64(R[3],R[7]);
        CE64(R[0],R[2]); CE64(R[1],R[3]); CE64(R[4],R[6]); CE64(R[5],R[7]);
        CE64(R[0],R[1]); CE64(R[2],R[3]); CE64(R[4],R[5]); CE64(R[6],R[7]);
    }

    __syncthreads();   // all sp reads done; overlay
    #pragma unroll
    for (int j = 0; j < 8; ++j) {
        khi[j*1024 + t] = (unsigned)(R[j] >> 32);
        klo[j*1024 + t] = (unsigned)R[j];
    }

    // tree merge: L lists -> L/2
    for (int L = 32; L >= 2; L >>= 1) {
        __syncthreads();
        unsigned long long A[8], Bv[8];
        int p = t >> 5;
        bool active = (p < (L >> 1));
        if (active) {
            int rowA = (2*p)*32 + q, rowB = (2*p + 1)*32 + q;
            #pragma unroll
            for (int j = 0; j < 8; ++j) {
                A[j]  = ((unsigned long long)khi[j*1024 + rowA] << 32) | klo[j*1024 + rowA];
                Bv[j] = ((unsigned long long)khi[j*1024 + rowB] << 32) | klo[j*1024 + rowB];
            }
        }
        __syncthreads();
        if (active) {
            unsigned long long C[8];
            #pragma unroll
            for (int j = 0; j < 8; ++j) {
                unsigned long long bb = Bv[7-j];
                C[j] = A[j] < bb ? A[j] : bb;
            }
            CE64(C[0],C[4]); CE64(C[1],C[5]); CE64(C[2],C[6]); CE64(C[3],C[7]);
            CE64(C[0],C[2]); CE64(C[1],C[3]); CE64(C[4],C[6]); CE64(C[5],C[7]);
            CE64(C[0],C[1]); CE64(C[2],C[3]); CE64(C[4],C[5]); CE64(C[6],C[7]);
            if (L > 2) {
                int rowO = p*32 + q;
                #pragma unroll
                for (int j = 0; j < 8; ++j) {
                    khi[j*1024 + rowO] = (unsigned)(C[j] >> 32);
                    klo[j*1024 + rowO] = (unsigned)C[j];
                }
            } else {
                #pragma unroll
                for (int j = 0; j < 8; ++j)
                    idxo[(b*NN + qbase + q)*KNB + j] = b*NN + (int)(C[j] & 0xFFFFFFFFu);
            }
        }
    }
}

// ---------------------------------------------------------------------------
// Generic fp32 tiled GEMM: C[M,*] (ldc) = epilogue(A[M,K] @ W[K,*] (ldw)).
// Tile 128x64, 256 threads, 4x8 micro-tile, BK=32.
// wstride!=0: W += blockIdx.y*wstride and W col base = 0 (merged-PQ mode).
// ---------------------------------------------------------------------------
__global__ __launch_bounds__(256) void k_gemm(
    const float* __restrict__ A, const float* __restrict__ W, float* __restrict__ C,
    int K, int ldw, int ldc,
    const float* __restrict__ bias, const float* __restrict__ gam,
    const float* __restrict__ bet, int act, int wstride)
{
    __shared__ float A_s[128*36];   // 18 KB
    __shared__ float W_s[32*64];    // 8 KB

    int t  = threadIdx.x;
    int tx = t & 7;        // col group: 8 cols
    int ty = t >> 3;       // row group: 4 rows
    int rb = blockIdx.x * 128;
    int cb = blockIdx.y * 64;
    const float* Wp = wstride ? (W + (size_t)blockIdx.y * wstride) : W;
    int wcb = wstride ? 0 : cb;

    float acc[4][8];
    #pragma unroll
    for (int i = 0; i < 4; ++i)
        #pragma unroll
        for (int j = 0; j < 8; ++j) acc[i][j] = 0.f;

    for (int k0 = 0; k0 < K; k0 += 32) {
        #pragma unroll
        for (int it = 0; it < 4; ++it) {
            int i = t + it*256;            // 0..1023
            int r = i >> 3, kq = (i & 7) * 4;
            float4 v = *(const float4*)&A[(rb + r)*K + k0 + kq];
            *(float4*)&A_s[r*36 + kq] = v;
        }
        #pragma unroll
        for (int it = 0; it < 2; ++it) {
            int i = t + it*256;            // 0..511
            int k = i >> 4, cq = (i & 15) * 4;
            float4 v = *(const float4*)&Wp[(k0 + k)*ldw + wcb + cq];
            *(float4*)&W_s[k*64 + cq] = v;
        }
        __syncthreads();

        #pragma unroll
        for (int kk = 0; kk < 32; kk += 2) {
            float2 a[4];
            #pragma unroll
            for (int i = 0; i < 4; ++i) a[i] = *(const float2*)&A_s[(ty*4 + i)*36 + kk];
            float4 w00 = *(const float4*)&W_s[ kk   *64 + tx*8];
            float4 w01 = *(const float4*)&W_s[ kk   *64 + tx*8 + 4];
            float4 w10 = *(const float4*)&W_s[(kk+1)*64 + tx*8];
            float4 w11 = *(const float4*)&W_s[(kk+1)*64 + tx*8 + 4];
            #pragma unroll
            for (int i = 0; i < 4; ++i) {
                float ax = a[i].x, ay = a[i].y;
                acc[i][0] = fmaf(ax, w00.x, acc[i][0]);
                acc[i][1] = fmaf(ax, w00.y, acc[i][1]);
                acc[i][2] = fmaf(ax, w00.z, acc[i][2]);
                acc[i][3] = fmaf(ax, w00.w, acc[i][3]);
                acc[i][4] = fmaf(ax, w01.x, acc[i][4]);
                acc[i][5] = fmaf(ax, w01.y, acc[i][5]);
                acc[i][6] = fmaf(ax, w01.z, acc[i][6]);
                acc[i][7] = fmaf(ax, w01.w, acc[i][7]);
                acc[i][0] = fmaf(ay, w10.x, acc[i][0]);
                acc[i][1] = fmaf(ay, w10.y, acc[i][1]);
                acc[i][2] = fmaf(ay, w10.z, acc[i][2]);
                acc[i][3] = fmaf(ay, w10.w, acc[i][3]);
                acc[i][4] = fmaf(ay, w11.x, acc[i][4]);
                acc[i][5] = fmaf(ay, w11.y, acc[i][5]);
                acc[i][6] = fmaf(ay, w11.z, acc[i][6]);
                acc[i][7] = fmaf(ay, w11.w, acc[i][7]);
            }
        }
        __syncthreads();
    }

    #pragma unroll
    for (int i = 0; i < 4; ++i) {
        int r = rb + ty*4 + i;
        int cbase = cb + tx*8;
        float vo[8];
        #pragma unroll
        for (int j = 0; j < 8; ++j) {
            int c = cbase + j;
            float v = acc[i][j];
            if (bias) v += bias[c];
            if (gam)  v = v * gam[c] + bet[c];
            if (act)  v = leaky(v);
            vo[j] = v;
        }
        *(float4*)&C[r*ldc + cbase]     = make_float4(vo[0], vo[1], vo[2], vo[3]);
        *(float4*)&C[r*ldc + cbase + 4] = make_float4(vo[4], vo[5], vo[6], vo[7]);
    }
}

// ---------------------------------------------------------------------------
// K4: gather-max edge conv + frequency weighting.
// ---------------------------------------------------------------------------
__global__ __launch_bounds__(256) void k_agg_multi(
    const float* __restrict__ PQ, const int* __restrict__ idx,
    const float* __restrict__ fw,
    const float* __restrict__ b2, const float* __restrict__ g2, const float* __restrict__ be2,
    float* __restrict__ multi)
{
    int lane = threadIdx.x & 63;
    int p = blockIdx.x * 4 + (threadIdx.x >> 6);
    float Pv = PQ[p*128 + lane] + b2[lane];
    float g = g2[lane], be = be2[lane];
    float mx = -1e30f;
    #pragma unroll
    for (int j = 0; j < KNB; ++j) {
        int nb = idx[p*KNB + j];
        float v = (Pv + PQ[nb*128 + 64 + lane]) * g + be;
        mx = fmaxf(mx, leaky(v));
    }
    float w0 = fw[p*3+0], w1 = fw[p*3+1], w2 = fw[p*3+2];
    multi[p*192 + lane]        = mx * w0;
    multi[p*192 + 64  + lane]  = mx * w1;
    multi[p*192 + 128 + lane]  = mx * w2;
}

// ---------------------------------------------------------------------------
// K7: delta = h2 @ Wf3 + bf3 (128 -> 3); out = x + 0.1*delta. wave per point.
// ---------------------------------------------------------------------------
__global__ __launch_bounds__(256) void k_out(
    const float* __restrict__ h2, const float* __restrict__ Wf3, const float* __restrict__ bf3,
    const float* __restrict__ x, float* __restrict__ out)
{
    int lane = threadIdx.x & 63;
    int p = blockIdx.x * 4 + (threadIdx.x >> 6);
    float v0 = h2[p*128 + lane], v1 = h2[p*128 + 64 + lane];
    #pragma unroll
    for (int l = 0; l < 3; ++l) {
        float s = v0 * Wf3[lane*3 + l] + v1 * Wf3[(64 + lane)*3 + l];
        #pragma unroll
        for (int off = 32; off; off >>= 1) s += __shfl_xor(s, off, 64);
        if (lane == l) out[p*3 + l] = x[p*3 + l] + 0.1f*(s + bf3[l]);
    }
}

// ---------------------------------------------------------------------------
extern "C" void kernel_launch(void* const* d_in, const int* in_sizes, int n_in,
                              void* d_out, int out_size, void* d_ws, size_t ws_size,
                              hipStream_t stream)
{
    const float* x    = (const float*)d_in[0];
    const float* W1   = (const float*)d_in[1];
    const float* b1   = (const float*)d_in[2];
    const float* g1   = (const float*)d_in[3];
    const float* be1  = (const float*)d_in[4];
    const float* W2   = (const float*)d_in[5];
    const float* b2   = (const float*)d_in[6];
    const float* g2   = (const float*)d_in[7];
    const float* be2  = (const float*)d_in[8];
    const float* Ws1  = (const float*)d_in[9];
    const float* bs1  = (const float*)d_in[10];
    const float* Ws2  = (const float*)d_in[11];
    const float* bs2  = (const float*)d_in[12];
    const float* Wf1  = (const float*)d_in[13];
    const float* bf1  = (const float*)d_in[14];
    const float* gf1  = (const float*)d_in[15];
    const float* bef1 = (const float*)d_in[16];
    const float* Wf2  = (const float*)d_in[17];
    const float* bf2  = (const float*)d_in[18];
    const float* gf2  = (const float*)d_in[19];
    const float* bef2 = (const float*)d_in[20];
    const float* Wf3  = (const float*)d_in[21];
    const float* bf3  = (const float*)d_in[22];
    float* out = (float*)d_out;

    char* ws = (char*)d_ws;
    float* feat  = (float*)(ws + 0);                  // 4 MB   [BN,64]
    float* fw    = (float*)(ws + (4u  << 20));        // .75 MB [BN,3]
    int*   idx   = (int*)  (ws + (5u  << 20));        // .5 MB  [BN,8]
    float* PQ    = (float*)(ws + (6u  << 20));        // 8 MB   [BN,128]
    float* multi = (float*)(ws + (14u << 20));        // 12 MB  [BN,192]
    float* h1    = (float*)(ws + 0);                  // 16 MB  [BN,256] (feat/fw/idx/PQ dead)
    float* h2    = (float*)(ws + (16u << 20));        // 8 MB   [BN,128] (multi dead)

    k_feat_fw<<<BN/4, 256, 0, stream>>>(x, W1, b1, g1, be1, Ws1, bs1, Ws2, bs2, feat, fw);
    k_knn<<<BB*64, 1024, 0, stream>>>(x, idx);
    // P|Q = feat @ {W2[:64], W2[64:]} in one dispatch (blockIdx.y selects half)
    k_gemm<<<dim3(BN/128, 2), 256, 0, stream>>>(feat, W2, PQ, 64, 64, 128,
                                                nullptr, nullptr, nullptr, 0, 64*64);
    k_agg_multi<<<BN/4, 256, 0, stream>>>(PQ, idx, fw, b2, g2, be2, multi);
    k_gemm<<<dim3(BN/128, H1D/64), 256, 0, stream>>>(multi, Wf1, h1, 192, H1D, H1D,
                                                     bf1, gf1, bef1, 1, 0);
    k_gemm<<<dim3(BN/128, H2D/64), 256, 0, stream>>>(h1, Wf2, h2, H1D, H2D, H2D,
                                                     bf2, gf2, bef2, 1, 0);
    k_out<<<BN/4, 256, 0, stream>>>(h2, Wf3, bf3, x, out);
}

// Round 5
// 180.539 us; speedup vs baseline: 1.4047x; 1.2763x over previous
//
#include <hip/hip_runtime.h>
#include <hip/hip_bf16.h>
#include <math.h>

// Problem constants: B=8, N=2048, C_IN=3, D=64, K=8, LEVELS=3, H1=256, H2=128
#define BB   8
#define NN   2048
#define BN   16384   // B*N
#define KNB  8

__device__ __forceinline__ float leaky(float v){ return v > 0.f ? v : 0.2f*v; }

using bf16x8 = __attribute__((ext_vector_type(8))) short;
using f32x16 = __attribute__((ext_vector_type(16))) float;

// ---------------------------------------------------------------------------
// K0: prep. blocks [0,4096): fw (suppressor), wave-per-point.
//          blocks [4096,4120): Wf1 [192][256] -> Wf1T bf16 [256][192]
//          blocks [4120,4136): Wf2 [256][128] -> Wf2T bf16 [128][256]
// ---------------------------------------------------------------------------
__global__ __launch_bounds__(256) void k_prep(
    const float* __restrict__ x,
    const float* __restrict__ Ws1, const float* __restrict__ bs1,
    const float* __restrict__ Ws2, const float* __restrict__ bs2,
    const float* __restrict__ Wf1, const float* __restrict__ Wf2,
    float* __restrict__ fw, __hip_bfloat16* __restrict__ Wf1T,
    __hip_bfloat16* __restrict__ Wf2T)
{
    int t = threadIdx.x;
    if (blockIdx.x < 4096) {
        int lane = t & 63;
        int p = blockIdx.x * 4 + (t >> 6);
        float x0 = x[p*3+0], x1 = x[p*3+1], x2 = x[p*3+2];
        int d = lane;
        float h = x0*Ws1[d] + x1*Ws1[64+d] + x2*Ws1[128+d] + bs1[d];
        h = fmaxf(h, 0.f);
        float s[3];
        #pragma unroll
        for (int l = 0; l < 3; ++l) {
            float v = h * Ws2[d*3 + l];
            #pragma unroll
            for (int off = 32; off; off >>= 1) v += __shfl_xor(v, off, 64);
            s[l] = v;
        }
        if (lane < 3) fw[p*3 + lane] = 1.f / (1.f + expf(-(s[lane] + bs2[lane])));
    } else if (blockIdx.x < 4120) {
        int base = (blockIdx.x - 4096) * 2048 + t * 8;
        #pragma unroll
        for (int j = 0; j < 8; ++j) {
            int e = base + j;              // e < 49152
            int n = e / 192, k = e % 192;
            Wf1T[e] = __float2bfloat16(Wf1[k*256 + n]);
        }
    } else {
        int base = (blockIdx.x - 4120) * 2048 + t * 8;
        #pragma unroll
        for (int j = 0; j < 8; ++j) {
            int e = base + j;              // e < 32768
            int n = e / 256, k = e % 256;
            Wf2T[e] = __float2bfloat16(Wf2[k*128 + n]);
        }
    }
}

// ---------------------------------------------------------------------------
// K1: exact KNN, top-8 smallest d2, ties -> lower index (stable top_k).
// u64 keys; Batcher sort-8 + bitonic min-merge per group of 8 candidates.
// Block: 1024 thr = 32 queries x 32 segments x 64 candidates.
// ---------------------------------------------------------------------------
#define CE64(a, b) { bool c_ = (b) < (a); unsigned long long mn_ = c_ ? (b) : (a); \
                     unsigned long long mx_ = c_ ? (a) : (b); (a) = mn_; (b) = mx_; }

__global__ __launch_bounds__(1024, 8) void k_knn(const float* __restrict__ x, int* __restrict__ idxo)
{
    __shared__ __align__(16) char smem[65536];
    float4*   sp  = (float4*)smem;               // 32 KB (scan phase)
    unsigned* khi = (unsigned*)smem;             // [8][1024] (merge phase)
    unsigned* klo = (unsigned*)(smem + 32768);

    int t = threadIdx.x;
    int b = blockIdx.x >> 6;
    int qbase = (blockIdx.x & 63) * 32;
    int q = t & 31, seg = t >> 5;

    for (int i = t; i < NN; i += 1024) {
        float a = x[(b*NN + i)*3 + 0];
        float c = x[(b*NN + i)*3 + 1];
        float e = x[(b*NN + i)*3 + 2];
        sp[i] = make_float4(a, c, e, a*a + c*c + e*e);
    }
    __syncthreads();

    float4 qv = sp[qbase + q];

    unsigned long long R[8];
    #pragma unroll
    for (int j = 0; j < 8; ++j) R[j] = 0xFFFFFFFFFFFFFFFFull;

    int m0 = seg * 64;
    #pragma unroll 2
    for (int g = 0; g < 8; ++g) {
        unsigned long long S[8];
        #pragma unroll
        for (int jj = 0; jj < 8; ++jj) {
            int m = m0 + g*8 + jj;
            float4 v = sp[m];
            float s = qv.x*v.x; s = fmaf(qv.y, v.y, s); s = fmaf(qv.z, v.z, s);
            float d2 = fmaf(-2.f, s, qv.w + v.w);
            unsigned ub = __float_as_uint(d2);
            unsigned u  = ub ^ (unsigned)(((int)ub >> 31) | 0x80000000);
            S[jj] = ((unsigned long long)u << 32) | (unsigned)m;
        }
        CE64(S[0],S[1]); CE64(S[2],S[3]); CE64(S[4],S[5]); CE64(S[6],S[7]);
        CE64(S[0],S[2]); CE64(S[1],S[3]); CE64(S[4],S[6]); CE64(S[5],S[7]);
        CE64(S[1],S[2]); CE64(S[5],S[6]);
        CE64(S[0],S[4]); CE64(S[1],S[5]); CE64(S[2],S[6]); CE64(S[3],S[7]);
        CE64(S[2],S[4]); CE64(S[3],S[5]);
        CE64(S[1],S[2]); CE64(S[3],S[4]); CE64(S[5],S[6]);
        #pragma unroll
        for (int j = 0; j < 8; ++j) {
            unsigned long long bb = S[7-j];
            R[j] = R[j] < bb ? R[j] : bb;
        }
        CE64(R[0],R[4]); CE64(R[1],R[5]); CE64(R[2],R[6]); CE64(R[3],R[7]);
        CE64(R[0],R[2]); CE64(R[1],R[3]); CE64(R[4],R[6]); CE64(R[5],R[7]);
        CE64(R[0],R[1]); CE64(R[2],R[3]); CE64(R[4],R[5]); CE64(R[6],R[7]);
    }

    __syncthreads();
    #pragma unroll
    for (int j = 0; j < 8; ++j) {
        khi[j*1024 + t] = (unsigned)(R[j] >> 32);
        klo[j*1024 + t] = (unsigned)R[j];
    }

    for (int L = 32; L >= 2; L >>= 1) {
        __syncthreads();
        unsigned long long A[8], Bv[8];
        int p = t >> 5;
        bool active = (p < (L >> 1));
        if (active) {
            int rowA = (2*p)*32 + q, rowB = (2*p + 1)*32 + q;
            #pragma unroll
            for (int j = 0; j < 8; ++j) {
                A[j]  = ((unsigned long long)khi[j*1024 + rowA] << 32) | klo[j*1024 + rowA];
                Bv[j] = ((unsigned long long)khi[j*1024 + rowB] << 32) | klo[j*1024 + rowB];
            }
        }
        __syncthreads();
        if (active) {
            unsigned long long C[8];
            #pragma unroll
            for (int j = 0; j < 8; ++j) {
                unsigned long long bb = Bv[7-j];
                C[j] = A[j] < bb ? A[j] : bb;
            }
            CE64(C[0],C[4]); CE64(C[1],C[5]); CE64(C[2],C[6]); CE64(C[3],C[7]);
            CE64(C[0],C[2]); CE64(C[1],C[3]); CE64(C[4],C[6]); CE64(C[5],C[7]);
            CE64(C[0],C[1]); CE64(C[2],C[3]); CE64(C[4],C[5]); CE64(C[6],C[7]);
            if (L > 2) {
                int rowO = p*32 + q;
                #pragma unroll
                for (int j = 0; j < 8; ++j) {
                    khi[j*1024 + rowO] = (unsigned)(C[j] >> 32);
                    klo[j*1024 + rowO] = (unsigned)C[j];
                }
            } else {
                #pragma unroll
                for (int j = 0; j < 8; ++j)
                    idxo[(b*NN + qbase + q)*KNB + j] = b*NN + (int)(C[j] & 0xFFFFFFFFu);
            }
        }
    }
}

// ---------------------------------------------------------------------------
// K2: fused feature-transform + PQ GEMM (fp32 exact).
// Tile 64 rows x 128 cols (P|Q), K=64. feat computed into LDS, never to HBM.
// ---------------------------------------------------------------------------
__global__ __launch_bounds__(256) void k_pq(
    const float* __restrict__ x,
    const float* __restrict__ W1, const float* __restrict__ b1,
    const float* __restrict__ g1, const float* __restrict__ be1,
    const float* __restrict__ W2, float* __restrict__ PQ)
{
    __shared__ float F_s[64*66];    // 16.9 KB
    __shared__ float W_s[32*132];   // 16.9 KB

    int t = threadIdx.x;
    int rb = blockIdx.x * 64;

    // feat: 4 groups of 64 threads (lane=d), 16 rows each
    {
        int d = t & 63, g = t >> 6;
        float w0 = W1[d], w1 = W1[64+d], w2 = W1[128+d];
        float bb = b1[d], gg = g1[d], ee = be1[d];
        #pragma unroll 4
        for (int i = 0; i < 16; ++i) {
            int r = g*16 + i;
            const float* xp = &x[(rb + r)*3];
            float f = xp[0]*w0 + xp[1]*w1 + xp[2]*w2 + bb;
            f = leaky(f*gg + ee);
            F_s[r*66 + d] = f;
        }
    }

    int tx = t & 15, ty = t >> 4;   // 8 cols x 4 rows micro-tile
    float acc[4][8];
    #pragma unroll
    for (int i = 0; i < 4; ++i)
        #pragma unroll
        for (int j = 0; j < 8; ++j) acc[i][j] = 0.f;

    for (int k0 = 0; k0 < 64; k0 += 32) {
        __syncthreads();
        // stage W' 32 x 128 : W'[k][c] = W2[k + 64*(c>=64)][c&63]
        #pragma unroll
        for (int it = 0; it < 2; ++it) {
            int i2 = t + it*256;                 // 0..511
            int k = i2 >> 4, c8 = (i2 & 15) * 8;
            const float* src = &W2[(k0 + k + (c8 >= 64 ? 64 : 0))*64 + (c8 & 63)];
            *(float4*)&W_s[k*132 + c8]     = *(const float4*)src;
            *(float4*)&W_s[k*132 + c8 + 4] = *(const float4*)(src + 4);
        }
        __syncthreads();
        #pragma unroll 4
        for (int kk = 0; kk < 32; ++kk) {
            float a[4];
            #pragma unroll
            for (int i = 0; i < 4; ++i) a[i] = F_s[(ty*4 + i)*66 + k0 + kk];
            float4 wA = *(const float4*)&W_s[kk*132 + tx*8];
            float4 wB = *(const float4*)&W_s[kk*132 + tx*8 + 4];
            #pragma unroll
            for (int i = 0; i < 4; ++i) {
                acc[i][0] = fmaf(a[i], wA.x, acc[i][0]);
                acc[i][1] = fmaf(a[i], wA.y, acc[i][1]);
                acc[i][2] = fmaf(a[i], wA.z, acc[i][2]);
                acc[i][3] = fmaf(a[i], wA.w, acc[i][3]);
                acc[i][4] = fmaf(a[i], wB.x, acc[i][4]);
                acc[i][5] = fmaf(a[i], wB.y, acc[i][5]);
                acc[i][6] = fmaf(a[i], wB.z, acc[i][6]);
                acc[i][7] = fmaf(a[i], wB.w, acc[i][7]);
            }
        }
    }

    #pragma unroll
    for (int i = 0; i < 4; ++i) {
        int r = rb + ty*4 + i;
        *(float4*)&PQ[r*128 + tx*8]     = make_float4(acc[i][0], acc[i][1], acc[i][2], acc[i][3]);
        *(float4*)&PQ[r*128 + tx*8 + 4] = make_float4(acc[i][4], acc[i][5], acc[i][6], acc[i][7]);
    }
}

// ---------------------------------------------------------------------------
// K3: gather-max edge conv + frequency weighting -> multi (bf16).
// ---------------------------------------------------------------------------
__global__ __launch_bounds__(256) void k_agg(
    const float* __restrict__ PQ, const int* __restrict__ idx,
    const float* __restrict__ fw,
    const float* __restrict__ b2, const float* __restrict__ g2, const float* __restrict__ be2,
    __hip_bfloat16* __restrict__ multi)
{
    int lane = threadIdx.x & 63;
    int p = blockIdx.x * 4 + (threadIdx.x >> 6);
    float Pv = PQ[p*128 + lane] + b2[lane];
    float g = g2[lane], be = be2[lane];
    float mx = -1e30f;
    #pragma unroll
    for (int j = 0; j < KNB; ++j) {
        int nb = idx[p*KNB + j];
        float v = (Pv + PQ[nb*128 + 64 + lane]) * g + be;
        mx = fmaxf(mx, leaky(v));
    }
    float w0 = fw[p*3+0], w1 = fw[p*3+1], w2 = fw[p*3+2];
    multi[p*192 + lane]       = __float2bfloat16(mx * w0);
    multi[p*192 + 64  + lane] = __float2bfloat16(mx * w1);
    multi[p*192 + 128 + lane] = __float2bfloat16(mx * w2);
}

// ---------------------------------------------------------------------------
// K4: h1 = leaky((multi @ Wf1 + bf1)*gf1 + bef1)  [bf16 MFMA, out bf16]
// M-tile 128, N-tile 64, BK=64. Wave w: rows w*32..+31, 2 frags of 32x32.
// ---------------------------------------------------------------------------
__global__ __launch_bounds__(256) void k_h1(
    const ushort* __restrict__ multi, const ushort* __restrict__ Wf1T,
    const float* __restrict__ bf1, const float* __restrict__ gf1,
    const float* __restrict__ bef1, __hip_bfloat16* __restrict__ h1)
{
    __shared__ ushort A_s[128*72];  // 18.4 KB
    __shared__ ushort B_s[64*72];   // 9.2 KB

    int t = threadIdx.x, w = t >> 6, lane = t & 63;
    int rb = blockIdx.x * 128, cb = blockIdx.y * 64;

    f32x16 acc[2];
    #pragma unroll
    for (int i = 0; i < 16; ++i) { acc[0][i] = 0.f; acc[1][i] = 0.f; }

    for (int k0 = 0; k0 < 192; k0 += 64) {
        #pragma unroll
        for (int it = 0; it < 4; ++it) {
            int i = t + it*256; int r = i >> 3, kq = (i & 7)*8;
            *(uint4*)&A_s[r*72 + kq] = *(const uint4*)&multi[(rb + r)*192 + k0 + kq];
        }
        #pragma unroll
        for (int it = 0; it < 2; ++it) {
            int i = t + it*256; int n = i >> 3, kq = (i & 7)*8;
            *(uint4*)&B_s[n*72 + kq] = *(const uint4*)&Wf1T[(cb + n)*192 + k0 + kq];
        }
        __syncthreads();
        int row = w*32 + (lane & 31);
        int kb = (lane >> 5)*8;
        #pragma unroll
        for (int s = 0; s < 4; ++s) {
            bf16x8 a  = *(const bf16x8*)&A_s[row*72 + s*16 + kb];
            bf16x8 b0 = *(const bf16x8*)&B_s[(lane & 31)*72 + s*16 + kb];
            bf16x8 b1 = *(const bf16x8*)&B_s[(32 + (lane & 31))*72 + s*16 + kb];
            acc[0] = __builtin_amdgcn_mfma_f32_32x32x16_bf16(a, b0, acc[0], 0, 0, 0);
            acc[1] = __builtin_amdgcn_mfma_f32_32x32x16_bf16(a, b1, acc[1], 0, 0, 0);
        }
        __syncthreads();
    }

    #pragma unroll
    for (int nb = 0; nb < 2; ++nb) {
        int c = cb + nb*32 + (lane & 31);
        float bv = bf1[c], gv = gf1[c], ev = bef1[c];
        #pragma unroll
        for (int r16 = 0; r16 < 16; ++r16) {
            int rr = (r16 & 3) + 8*(r16 >> 2) + 4*(lane >> 5);
            float v = leaky((acc[nb][r16] + bv)*gv + ev);
            h1[(rb + w*32 + rr)*256 + c] = __float2bfloat16(v);
        }
    }
}

// ---------------------------------------------------------------------------
// K5: h2 = leaky((h1 @ Wf2 + bf2)*gf2 + bef2); delta = h2 @ Wf3 + bf3;
//     out = x + 0.1*delta.   [bf16 MFMA + fused epilogue reduction]
// M-tile 128, N = 128 (full), BK=64. Wave w: rows w*32..+31, 4 frags.
// ---------------------------------------------------------------------------
__global__ __launch_bounds__(256) void k_h2out(
    const ushort* __restrict__ h1, const ushort* __restrict__ Wf2T,
    const float* __restrict__ bf2, const float* __restrict__ gf2,
    const float* __restrict__ bef2,
    const float* __restrict__ Wf3, const float* __restrict__ bf3,
    const float* __restrict__ x, float* __restrict__ out)
{
    __shared__ ushort A_s[128*72];  // 18.4 KB
    __shared__ ushort B_s[128*72];  // 18.4 KB

    int t = threadIdx.x, w = t >> 6, lane = t & 63;
    int rb = blockIdx.x * 128;

    f32x16 acc[4];
    #pragma unroll
    for (int nb = 0; nb < 4; ++nb)
        #pragma unroll
        for (int i = 0; i < 16; ++i) acc[nb][i] = 0.f;

    for (int k0 = 0; k0 < 256; k0 += 64) {
        #pragma unroll
        for (int it = 0; it < 4; ++it) {
            int i = t + it*256; int r = i >> 3, kq = (i & 7)*8;
            *(uint4*)&A_s[r*72 + kq] = *(const uint4*)&h1[(rb + r)*256 + k0 + kq];
        }
        #pragma unroll
        for (int it = 0; it < 4; ++it) {
            int i = t + it*256; int n = i >> 3, kq = (i & 7)*8;
            *(uint4*)&B_s[n*72 + kq] = *(const uint4*)&Wf2T[n*256 + k0 + kq];
        }
        __syncthreads();
        int row = w*32 + (lane & 31);
        int kb = (lane >> 5)*8;
        #pragma unroll
        for (int s = 0; s < 4; ++s) {
            bf16x8 a = *(const bf16x8*)&A_s[row*72 + s*16 + kb];
            #pragma unroll
            for (int nb = 0; nb < 4; ++nb) {
                bf16x8 b = *(const bf16x8*)&B_s[(nb*32 + (lane & 31))*72 + s*16 + kb];
                acc[nb] = __builtin_amdgcn_mfma_f32_32x32x16_bf16(a, b, acc[nb], 0, 0, 0);
            }
        }
        __syncthreads();
    }

    // epilogue: h2 affine+leaky, then per-row delta = h2 . Wf3 (cols split
    // across the 32 lanes of each half-wave; butterfly-reduce, lanes 0..2 write)
    float bv[4], gv[4], ev[4], w3[4][3];
    #pragma unroll
    for (int nb = 0; nb < 4; ++nb) {
        int c = nb*32 + (lane & 31);
        bv[nb] = bf2[c]; gv[nb] = gf2[c]; ev[nb] = bef2[c];
        #pragma unroll
        for (int l = 0; l < 3; ++l) w3[nb][l] = Wf3[c*3 + l];
    }
    float b30 = bf3[0], b31 = bf3[1], b32 = bf3[2];

    #pragma unroll
    for (int r16 = 0; r16 < 16; ++r16) {
        float d0 = 0.f, d1 = 0.f, d2 = 0.f;
        #pragma unroll
        for (int nb = 0; nb < 4; ++nb) {
            float v = leaky((acc[nb][r16] + bv[nb])*gv[nb] + ev[nb]);
            d0 = fmaf(v, w3[nb][0], d0);
            d1 = fmaf(v, w3[nb][1], d1);
            d2 = fmaf(v, w3[nb][2], d2);
        }
        #pragma unroll
        for (int off = 16; off; off >>= 1) {   // reduce within each 32-lane half
            d0 += __shfl_xor(d0, off, 64);
            d1 += __shfl_xor(d1, off, 64);
            d2 += __shfl_xor(d2, off, 64);
        }
        int row = rb + w*32 + (r16 & 3) + 8*(r16 >> 2) + 4*(lane >> 5);
        int l = lane & 31;
        if (l < 3) {
            float dl = (l == 0) ? d0 : (l == 1 ? d1 : d2);
            float bl = (l == 0) ? b30 : (l == 1 ? b31 : b32);
            out[row*3 + l] = x[row*3 + l] + 0.1f*(dl + bl);
        }
    }
}

// ---------------------------------------------------------------------------
extern "C" void kernel_launch(void* const* d_in, const int* in_sizes, int n_in,
                              void* d_out, int out_size, void* d_ws, size_t ws_size,
                              hipStream_t stream)
{
    const float* x    = (const float*)d_in[0];
    const float* W1   = (const float*)d_in[1];
    const float* b1   = (const float*)d_in[2];
    const float* g1   = (const float*)d_in[3];
    const float* be1  = (const float*)d_in[4];
    const float* W2   = (const float*)d_in[5];
    const float* b2   = (const float*)d_in[6];
    const float* g2   = (const float*)d_in[7];
    const float* be2  = (const float*)d_in[8];
    const float* Ws1  = (const float*)d_in[9];
    const float* bs1  = (const float*)d_in[10];
    const float* Ws2  = (const float*)d_in[11];
    const float* bs2  = (const float*)d_in[12];
    const float* Wf1  = (const float*)d_in[13];
    const float* bf1  = (const float*)d_in[14];
    const float* gf1  = (const float*)d_in[15];
    const float* bef1 = (const float*)d_in[16];
    const float* Wf2  = (const float*)d_in[17];
    const float* bf2  = (const float*)d_in[18];
    const float* gf2  = (const float*)d_in[19];
    const float* bef2 = (const float*)d_in[20];
    const float* Wf3  = (const float*)d_in[21];
    const float* bf3  = (const float*)d_in[22];
    float* out = (float*)d_out;

    char* ws = (char*)d_ws;
    float*          fw    = (float*)         (ws + 0);            // 196 KB
    int*            idx   = (int*)           (ws + (1u  << 20));  // 512 KB
    __hip_bfloat16* Wf1T  = (__hip_bfloat16*)(ws + (2u  << 20));  // 96 KB
    __hip_bfloat16* Wf2T  = (__hip_bfloat16*)(ws + (3u  << 20));  // 64 KB
    float*          PQ    = (float*)         (ws + (4u  << 20));  // 8 MB
    __hip_bfloat16* multi = (__hip_bfloat16*)(ws + (12u << 20));  // 6 MB
    __hip_bfloat16* h1    = (__hip_bfloat16*)(ws + (20u << 20));  // 8 MB

    k_prep<<<4136, 256, 0, stream>>>(x, Ws1, bs1, Ws2, bs2, Wf1, Wf2, fw, Wf1T, Wf2T);
    k_knn<<<BB*64, 1024, 0, stream>>>(x, idx);
    k_pq<<<BN/64, 256, 0, stream>>>(x, W1, b1, g1, be1, W2, PQ);
    k_agg<<<BN/4, 256, 0, stream>>>(PQ, idx, fw, b2, g2, be2, multi);
    k_h1<<<dim3(BN/128, 4), 256, 0, stream>>>((const ushort*)multi, (const ushort*)Wf1T,
                                              bf1, gf1, bef1, h1);
    k_h2out<<<dim3(BN/128, 1), 256, 0, stream>>>((const ushort*)h1, (const ushort*)Wf2T,
                                                 bf2, gf2, bef2, Wf3, bf3, x, out);
}

// Round 6
// 176.670 us; speedup vs baseline: 1.4355x; 1.0219x over previous
//
#include <hip/hip_runtime.h>
#include <hip/hip_bf16.h>
#include <math.h>

// Problem constants: B=8, N=2048, C_IN=3, D=64, K=8, LEVELS=3, H1=256, H2=128
#define BB   8
#define NN   2048
#define BN   16384   // B*N
#define KNB  8

__device__ __forceinline__ float leaky(float v){ return v > 0.f ? v : 0.2f*v; }

// RNE float->bf16 bits (finite inputs), matches __float2bfloat16 rounding
__device__ __forceinline__ ushort f2bf(float f){
    unsigned u = __float_as_uint(f);
    return (ushort)((u + 0x7FFFu + ((u >> 16) & 1u)) >> 16);
}
__device__ __forceinline__ float bf2f(ushort h){
    return __uint_as_float(((unsigned)h) << 16);
}

using bf16x8 = __attribute__((ext_vector_type(8))) short;
using f32x16 = __attribute__((ext_vector_type(16))) float;

// ---------------------------------------------------------------------------
// K1: fused feature-transform + PQ GEMM (fp32 math) + weight-transpose tail.
// blocks [0,256): tile 64 rows x 128 cols; P fp32 [BN][64], Q bf16 [BN][64].
// blocks [256,280): Wf1 [192][256] -> Wf1T bf16 [256][192]
// blocks [280,296): Wf2 [256][128] -> Wf2T bf16 [128][256]
// ---------------------------------------------------------------------------
__global__ __launch_bounds__(256) void k_pq(
    const float* __restrict__ x,
    const float* __restrict__ W1, const float* __restrict__ b1,
    const float* __restrict__ g1, const float* __restrict__ be1,
    const float* __restrict__ W2,
    const float* __restrict__ Wf1, const float* __restrict__ Wf2,
    float* __restrict__ P, ushort* __restrict__ Qb,
    ushort* __restrict__ Wf1T, ushort* __restrict__ Wf2T)
{
    int t = threadIdx.x;
    int bid = blockIdx.x;
    if (bid >= 256) {
        if (bid < 280) {
            int base = (bid - 256) * 2048 + t * 8;
            #pragma unroll
            for (int j = 0; j < 8; ++j) {
                int e = base + j;              // e < 49152
                int n = e / 192, k = e % 192;
                Wf1T[e] = f2bf(Wf1[k*256 + n]);
            }
        } else {
            int base = (bid - 280) * 2048 + t * 8;
            #pragma unroll
            for (int j = 0; j < 8; ++j) {
                int e = base + j;              // e < 32768
                int n = e / 256, k = e % 256;
                Wf2T[e] = f2bf(Wf2[k*128 + n]);
            }
        }
        return;
    }

    __shared__ float F_s[64*66];    // 16.9 KB
    __shared__ float W_s[32*132];   // 16.9 KB

    int rb = bid * 64;

    // feat: 4 groups of 64 threads (lane=d), 16 rows each
    {
        int d = t & 63, g = t >> 6;
        float w0 = W1[d], w1 = W1[64+d], w2 = W1[128+d];
        float bb = b1[d], gg = g1[d], ee = be1[d];
        #pragma unroll 4
        for (int i = 0; i < 16; ++i) {
            int r = g*16 + i;
            const float* xp = &x[(rb + r)*3];
            float f = xp[0]*w0 + xp[1]*w1 + xp[2]*w2 + bb;
            f = leaky(f*gg + ee);
            F_s[r*66 + d] = f;
        }
    }

    int tx = t & 15, ty = t >> 4;   // 8 cols x 4 rows micro-tile
    float acc[4][8];
    #pragma unroll
    for (int i = 0; i < 4; ++i)
        #pragma unroll
        for (int j = 0; j < 8; ++j) acc[i][j] = 0.f;

    for (int k0 = 0; k0 < 64; k0 += 32) {
        __syncthreads();
        // stage W' 32 x 128 : W'[k][c] = W2[k + 64*(c>=64)][c&63]
        #pragma unroll
        for (int it = 0; it < 2; ++it) {
            int i2 = t + it*256;                 // 0..511
            int k = i2 >> 4, c8 = (i2 & 15) * 8;
            const float* src = &W2[(k0 + k + (c8 >= 64 ? 64 : 0))*64 + (c8 & 63)];
            *(float4*)&W_s[k*132 + c8]     = *(const float4*)src;
            *(float4*)&W_s[k*132 + c8 + 4] = *(const float4*)(src + 4);
        }
        __syncthreads();
        #pragma unroll 4
        for (int kk = 0; kk < 32; ++kk) {
            float a[4];
            #pragma unroll
            for (int i = 0; i < 4; ++i) a[i] = F_s[(ty*4 + i)*66 + k0 + kk];
            float4 wA = *(const float4*)&W_s[kk*132 + tx*8];
            float4 wB = *(const float4*)&W_s[kk*132 + tx*8 + 4];
            #pragma unroll
            for (int i = 0; i < 4; ++i) {
                acc[i][0] = fmaf(a[i], wA.x, acc[i][0]);
                acc[i][1] = fmaf(a[i], wA.y, acc[i][1]);
                acc[i][2] = fmaf(a[i], wA.z, acc[i][2]);
                acc[i][3] = fmaf(a[i], wA.w, acc[i][3]);
                acc[i][4] = fmaf(a[i], wB.x, acc[i][4]);
                acc[i][5] = fmaf(a[i], wB.y, acc[i][5]);
                acc[i][6] = fmaf(a[i], wB.z, acc[i][6]);
                acc[i][7] = fmaf(a[i], wB.w, acc[i][7]);
            }
        }
    }

    #pragma unroll
    for (int i = 0; i < 4; ++i) {
        int r = rb + ty*4 + i;
        if (tx < 8) {        // cols 0..63 -> P (fp32)
            *(float4*)&P[r*64 + tx*8]     = make_float4(acc[i][0], acc[i][1], acc[i][2], acc[i][3]);
            *(float4*)&P[r*64 + tx*8 + 4] = make_float4(acc[i][4], acc[i][5], acc[i][6], acc[i][7]);
        } else {             // cols 64..127 -> Q (bf16)
            union { ushort u[8]; uint4 v; } pk;
            #pragma unroll
            for (int j = 0; j < 8; ++j) pk.u[j] = f2bf(acc[i][j]);
            *(uint4*)&Qb[r*64 + (tx - 8)*8] = pk.v;
        }
    }
}

// ---------------------------------------------------------------------------
// K2: exact KNN, top-8 smallest d2, ties -> lower index (stable top_k).
// u64 keys (hi = float bits of clamped d2, lo = local index).
// Batcher sort-8 + bitonic min-merge per group of 8 candidates.
// Block: 1024 thr = 32 queries x 32 segments x 64 candidates.
// ---------------------------------------------------------------------------
#define CE64(a, b) { bool c_ = (b) < (a); unsigned long long mn_ = c_ ? (b) : (a); \
                     unsigned long long mx_ = c_ ? (a) : (b); (a) = mn_; (b) = mx_; }

__global__ __launch_bounds__(1024, 8) void k_knn(const float* __restrict__ x, int* __restrict__ idxo)
{
    __shared__ __align__(16) char smem[65536];
    float4*   sp  = (float4*)smem;               // 32 KB (scan phase)
    unsigned* khi = (unsigned*)smem;             // [8][1024] (merge phase)
    unsigned* klo = (unsigned*)(smem + 32768);

    int t = threadIdx.x;
    int b = blockIdx.x >> 6;
    int qbase = (blockIdx.x & 63) * 32;
    int q = t & 31, seg = t >> 5;

    for (int i = t; i < NN; i += 1024) {
        float a = x[(b*NN + i)*3 + 0];
        float c = x[(b*NN + i)*3 + 1];
        float e = x[(b*NN + i)*3 + 2];
        sp[i] = make_float4(a, c, e, a*a + c*c + e*e);
    }
    __syncthreads();

    float4 qv = sp[qbase + q];

    unsigned long long R[8];
    #pragma unroll
    for (int j = 0; j < 8; ++j) R[j] = 0xFFFFFFFFFFFFFFFFull;

    int m0 = seg * 64;
    #pragma unroll 2
    for (int g = 0; g < 8; ++g) {
        unsigned long long S[8];
        #pragma unroll
        for (int jj = 0; jj < 8; ++jj) {
            int m = m0 + g*8 + jj;
            float4 v = sp[m];
            float s = qv.x*v.x; s = fmaf(qv.y, v.y, s); s = fmaf(qv.z, v.z, s);
            float d2 = fmaf(-2.f, s, qv.w + v.w);
            // clamp: non-negative float bits are order-monotone; only the
            // self-point can go (tiny) negative by cancellation
            unsigned u = __float_as_uint(fmaxf(d2, 0.f));
            S[jj] = ((unsigned long long)u << 32) | (unsigned)m;
        }
        CE64(S[0],S[1]); CE64(S[2],S[3]); CE64(S[4],S[5]); CE64(S[6],S[7]);
        CE64(S[0],S[2]); CE64(S[1],S[3]); CE64(S[4],S[6]); CE64(S[5],S[7]);
        CE64(S[1],S[2]); CE64(S[5],S[6]);
        CE64(S[0],S[4]); CE64(S[1],S[5]); CE64(S[2],S[6]); CE64(S[3],S[7]);
        CE64(S[2],S[4]); CE64(S[3],S[5]);
        CE64(S[1],S[2]); CE64(S[3],S[4]); CE64(S[5],S[6]);
        #pragma unroll
        for (int j = 0; j < 8; ++j) {
            unsigned long long bb = S[7-j];
            R[j] = R[j] < bb ? R[j] : bb;
        }
        CE64(R[0],R[4]); CE64(R[1],R[5]); CE64(R[2],R[6]); CE64(R[3],R[7]);
        CE64(R[0],R[2]); CE64(R[1],R[3]); CE64(R[4],R[6]); CE64(R[5],R[7]);
        CE64(R[0],R[1]); CE64(R[2],R[3]); CE64(R[4],R[5]); CE64(R[6],R[7]);
    }

    __syncthreads();
    #pragma unroll
    for (int j = 0; j < 8; ++j) {
        khi[j*1024 + t] = (unsigned)(R[j] >> 32);
        klo[j*1024 + t] = (unsigned)R[j];
    }

    for (int L = 32; L >= 2; L >>= 1) {
        __syncthreads();
        unsigned long long A[8], Bv[8];
        int p = t >> 5;
        bool active = (p < (L >> 1));
        if (active) {
            int rowA = (2*p)*32 + q, rowB = (2*p + 1)*32 + q;
            #pragma unroll
            for (int j = 0; j < 8; ++j) {
                A[j]  = ((unsigned long long)khi[j*1024 + rowA] << 32) | klo[j*1024 + rowA];
                Bv[j] = ((unsigned long long)khi[j*1024 + rowB] << 32) | klo[j*1024 + rowB];
            }
        }
        __syncthreads();
        if (active) {
            unsigned long long C[8];
            #pragma unroll
            for (int j = 0; j < 8; ++j) {
                unsigned long long bb = Bv[7-j];
                C[j] = A[j] < bb ? A[j] : bb;
            }
            CE64(C[0],C[4]); CE64(C[1],C[5]); CE64(C[2],C[6]); CE64(C[3],C[7]);
            CE64(C[0],C[2]); CE64(C[1],C[3]); CE64(C[4],C[6]); CE64(C[5],C[7]);
            CE64(C[0],C[1]); CE64(C[2],C[3]); CE64(C[4],C[5]); CE64(C[6],C[7]);
            if (L > 2) {
                int rowO = p*32 + q;
                #pragma unroll
                for (int j = 0; j < 8; ++j) {
                    khi[j*1024 + rowO] = (unsigned)(C[j] >> 32);
                    klo[j*1024 + rowO] = (unsigned)C[j];
                }
            } else {
                #pragma unroll
                for (int j = 0; j < 8; ++j)
                    idxo[(b*NN + qbase + q)*KNB + j] = b*NN + (int)(C[j] & 0xFFFFFFFFu);
            }
        }
    }
}

// ---------------------------------------------------------------------------
// K3: fused suppressor (fw) + gather-max edge conv + frequency weighting.
// wave per point, lane = d. Q gathered as bf16 (2 MB -> L2-resident).
// ---------------------------------------------------------------------------
__global__ __launch_bounds__(256) void k_agg(
    const float* __restrict__ x,
    const float* __restrict__ P, const ushort* __restrict__ Qb,
    const int* __restrict__ idx,
    const float* __restrict__ Ws1, const float* __restrict__ bs1,
    const float* __restrict__ Ws2, const float* __restrict__ bs2,
    const float* __restrict__ b2, const float* __restrict__ g2,
    const float* __restrict__ be2,
    ushort* __restrict__ multi)
{
    int lane = threadIdx.x & 63;
    int p = blockIdx.x * 4 + (threadIdx.x >> 6);

    // suppressor weights (all lanes end with the full sums via butterfly)
    float x0 = x[p*3+0], x1 = x[p*3+1], x2 = x[p*3+2];
    float h = fmaxf(x0*Ws1[lane] + x1*Ws1[64+lane] + x2*Ws1[128+lane] + bs1[lane], 0.f);
    float s[3];
    #pragma unroll
    for (int l = 0; l < 3; ++l) {
        float v = h * Ws2[lane*3 + l];
        #pragma unroll
        for (int off = 32; off; off >>= 1) v += __shfl_xor(v, off, 64);
        s[l] = v + bs2[l];
    }
    float fw0 = 1.f/(1.f + expf(-s[0]));
    float fw1 = 1.f/(1.f + expf(-s[1]));
    float fw2 = 1.f/(1.f + expf(-s[2]));

    // gather-max edge conv
    float Pv = P[p*64 + lane] + b2[lane];
    float g = g2[lane], be = be2[lane];
    float mx = -1e30f;
    #pragma unroll
    for (int j = 0; j < KNB; ++j) {
        int nb = idx[p*KNB + j];
        float qv = bf2f(Qb[nb*64 + lane]);
        float v = (Pv + qv) * g + be;
        mx = fmaxf(mx, leaky(v));
    }
    multi[p*192 + lane]       = f2bf(mx * fw0);
    multi[p*192 + 64  + lane] = f2bf(mx * fw1);
    multi[p*192 + 128 + lane] = f2bf(mx * fw2);
}

// ---------------------------------------------------------------------------
// K4: h1 = leaky((multi @ Wf1 + bf1)*gf1 + bef1)  [bf16 MFMA, out bf16]
// M-tile 128, N-tile 64, BK=64. Wave w: rows w*32..+31, 2 frags of 32x32.
// ---------------------------------------------------------------------------
__global__ __launch_bounds__(256) void k_h1(
    const ushort* __restrict__ multi, const ushort* __restrict__ Wf1T,
    const float* __restrict__ bf1, const float* __restrict__ gf1,
    const float* __restrict__ bef1, ushort* __restrict__ h1)
{
    __shared__ ushort A_s[128*72];  // 18.4 KB
    __shared__ ushort B_s[64*72];   // 9.2 KB

    int t = threadIdx.x, w = t >> 6, lane = t & 63;
    int rb = blockIdx.x * 128, cb = blockIdx.y * 64;

    f32x16 acc[2];
    #pragma unroll
    for (int i = 0; i < 16; ++i) { acc[0][i] = 0.f; acc[1][i] = 0.f; }

    for (int k0 = 0; k0 < 192; k0 += 64) {
        #pragma unroll
        for (int it = 0; it < 4; ++it) {
            int i = t + it*256; int r = i >> 3, kq = (i & 7)*8;
            *(uint4*)&A_s[r*72 + kq] = *(const uint4*)&multi[(rb + r)*192 + k0 + kq];
        }
        #pragma unroll
        for (int it = 0; it < 2; ++it) {
            int i = t + it*256; int n = i >> 3, kq = (i & 7)*8;
            *(uint4*)&B_s[n*72 + kq] = *(const uint4*)&Wf1T[(cb + n)*192 + k0 + kq];
        }
        __syncthreads();
        int row = w*32 + (lane & 31);
        int kb = (lane >> 5)*8;
        #pragma unroll
        for (int s = 0; s < 4; ++s) {
            bf16x8 a  = *(const bf16x8*)&A_s[row*72 + s*16 + kb];
            bf16x8 b0 = *(const bf16x8*)&B_s[(lane & 31)*72 + s*16 + kb];
            bf16x8 b1 = *(const bf16x8*)&B_s[(32 + (lane & 31))*72 + s*16 + kb];
            acc[0] = __builtin_amdgcn_mfma_f32_32x32x16_bf16(a, b0, acc[0], 0, 0, 0);
            acc[1] = __builtin_amdgcn_mfma_f32_32x32x16_bf16(a, b1, acc[1], 0, 0, 0);
        }
        __syncthreads();
    }

    #pragma unroll
    for (int nb = 0; nb < 2; ++nb) {
        int c = cb + nb*32 + (lane & 31);
        float bv = bf1[c], gv = gf1[c], ev = bef1[c];
        #pragma unroll
        for (int r16 = 0; r16 < 16; ++r16) {
            int rr = (r16 & 3) + 8*(r16 >> 2) + 4*(lane >> 5);
            float v = leaky((acc[nb][r16] + bv)*gv + ev);
            h1[(rb + w*32 + rr)*256 + c] = f2bf(v);
        }
    }
}

// ---------------------------------------------------------------------------
// K5: h2 = leaky((h1 @ Wf2 + bf2)*gf2 + bef2); delta = h2 @ Wf3 + bf3;
//     out = x + 0.1*delta.   [bf16 MFMA + fused epilogue reduction]
// ---------------------------------------------------------------------------
__global__ __launch_bounds__(256) void k_h2out(
    const ushort* __restrict__ h1, const ushort* __restrict__ Wf2T,
    const float* __restrict__ bf2, const float* __restrict__ gf2,
    const float* __restrict__ bef2,
    const float* __restrict__ Wf3, const float* __restrict__ bf3,
    const float* __restrict__ x, float* __restrict__ out)
{
    __shared__ ushort A_s[128*72];  // 18.4 KB
    __shared__ ushort B_s[128*72];  // 18.4 KB

    int t = threadIdx.x, w = t >> 6, lane = t & 63;
    int rb = blockIdx.x * 128;

    f32x16 acc[4];
    #pragma unroll
    for (int nb = 0; nb < 4; ++nb)
        #pragma unroll
        for (int i = 0; i < 16; ++i) acc[nb][i] = 0.f;

    for (int k0 = 0; k0 < 256; k0 += 64) {
        #pragma unroll
        for (int it = 0; it < 4; ++it) {
            int i = t + it*256; int r = i >> 3, kq = (i & 7)*8;
            *(uint4*)&A_s[r*72 + kq] = *(const uint4*)&h1[(rb + r)*256 + k0 + kq];
        }
        #pragma unroll
        for (int it = 0; it < 4; ++it) {
            int i = t + it*256; int n = i >> 3, kq = (i & 7)*8;
            *(uint4*)&B_s[n*72 + kq] = *(const uint4*)&Wf2T[n*256 + k0 + kq];
        }
        __syncthreads();
        int row = w*32 + (lane & 31);
        int kb = (lane >> 5)*8;
        #pragma unroll
        for (int s = 0; s < 4; ++s) {
            bf16x8 a = *(const bf16x8*)&A_s[row*72 + s*16 + kb];
            #pragma unroll
            for (int nb = 0; nb < 4; ++nb) {
                bf16x8 b = *(const bf16x8*)&B_s[(nb*32 + (lane & 31))*72 + s*16 + kb];
                acc[nb] = __builtin_amdgcn_mfma_f32_32x32x16_bf16(a, b, acc[nb], 0, 0, 0);
            }
        }
        __syncthreads();
    }

    float bv[4], gv[4], ev[4], w3[4][3];
    #pragma unroll
    for (int nb = 0; nb < 4; ++nb) {
        int c = nb*32 + (lane & 31);
        bv[nb] = bf2[c]; gv[nb] = gf2[c]; ev[nb] = bef2[c];
        #pragma unroll
        for (int l = 0; l < 3; ++l) w3[nb][l] = Wf3[c*3 + l];
    }
    float b30 = bf3[0], b31 = bf3[1], b32 = bf3[2];

    #pragma unroll
    for (int r16 = 0; r16 < 16; ++r16) {
        float d0 = 0.f, d1 = 0.f, d2 = 0.f;
        #pragma unroll
        for (int nb = 0; nb < 4; ++nb) {
            float v = leaky((acc[nb][r16] + bv[nb])*gv[nb] + ev[nb]);
            d0 = fmaf(v, w3[nb][0], d0);
            d1 = fmaf(v, w3[nb][1], d1);
            d2 = fmaf(v, w3[nb][2], d2);
        }
        #pragma unroll
        for (int off = 16; off; off >>= 1) {   // reduce within each 32-lane half
            d0 += __shfl_xor(d0, off, 64);
            d1 += __shfl_xor(d1, off, 64);
            d2 += __shfl_xor(d2, off, 64);
        }
        int row = rb + w*32 + (r16 & 3) + 8*(r16 >> 2) + 4*(lane >> 5);
        int l = lane & 31;
        if (l < 3) {
            float dl = (l == 0) ? d0 : (l == 1 ? d1 : d2);
            float bl = (l == 0) ? b30 : (l == 1 ? b31 : b32);
            out[row*3 + l] = x[row*3 + l] + 0.1f*(dl + bl);
        }
    }
}

// ---------------------------------------------------------------------------
extern "C" void kernel_launch(void* const* d_in, const int* in_sizes, int n_in,
                              void* d_out, int out_size, void* d_ws, size_t ws_size,
                              hipStream_t stream)
{
    const float* x    = (const float*)d_in[0];
    const float* W1   = (const float*)d_in[1];
    const float* b1   = (const float*)d_in[2];
    const float* g1   = (const float*)d_in[3];
    const float* be1  = (const float*)d_in[4];
    const float* W2   = (const float*)d_in[5];
    const float* b2   = (const float*)d_in[6];
    const float* g2   = (const float*)d_in[7];
    const float* be2  = (const float*)d_in[8];
    const float* Ws1  = (const float*)d_in[9];
    const float* bs1  = (const float*)d_in[10];
    const float* Ws2  = (const float*)d_in[11];
    const float* bs2  = (const float*)d_in[12];
    const float* Wf1  = (const float*)d_in[13];
    const float* bf1  = (const float*)d_in[14];
    const float* gf1  = (const float*)d_in[15];
    const float* bef1 = (const float*)d_in[16];
    const float* Wf2  = (const float*)d_in[17];
    const float* bf2  = (const float*)d_in[18];
    const float* gf2  = (const float*)d_in[19];
    const float* bef2 = (const float*)d_in[20];
    const float* Wf3  = (const float*)d_in[21];
    const float* bf3  = (const float*)d_in[22];
    float* out = (float*)d_out;

    char* ws = (char*)d_ws;
    int*    idx   = (int*)   (ws + 0);             // 512 KB
    ushort* Wf1T  = (ushort*)(ws + (1u << 20));    // 96 KB
    ushort* Wf2T  = (ushort*)(ws + (1u << 20) + (512u << 10)); // 64 KB
    float*  P     = (float*) (ws + (2u  << 20));   // 4 MB   [BN][64] fp32
    ushort* Qb    = (ushort*)(ws + (6u  << 20));   // 2 MB   [BN][64] bf16
    ushort* multi = (ushort*)(ws + (8u  << 20));   // 6 MB   [BN][192] bf16
    ushort* h1    = (ushort*)(ws + (14u << 20));   // 8 MB   [BN][256] bf16

    k_pq<<<296, 256, 0, stream>>>(x, W1, b1, g1, be1, W2, Wf1, Wf2, P, Qb, Wf1T, Wf2T);
    k_knn<<<BB*64, 1024, 0, stream>>>(x, idx);
    k_agg<<<BN/4, 256, 0, stream>>>(x, P, Qb, idx, Ws1, bs1, Ws2, bs2, b2, g2, be2, multi);
    k_h1<<<dim3(BN/128, 4), 256, 0, stream>>>(multi, Wf1T, bf1, gf1, bef1, h1);
    k_h2out<<<dim3(BN/128, 1), 256, 0, stream>>>(h1, Wf2T, bf2, gf2, bef2, Wf3, bf3, x, out);
}

// Round 7
// 172.079 us; speedup vs baseline: 1.4738x; 1.0267x over previous
//
#include <hip/hip_runtime.h>
#include <hip/hip_bf16.h>
#include <math.h>

// Problem constants: B=8, N=2048, C_IN=3, D=64, K=8, LEVELS=3, H1=256, H2=128
#define BB   8
#define NN   2048
#define BN   16384   // B*N
#define KNB  8

__device__ __forceinline__ float leaky(float v){ return v > 0.f ? v : 0.2f*v; }

// RNE float->bf16 bits (finite inputs), matches __float2bfloat16 rounding
__device__ __forceinline__ ushort f2bf(float f){
    unsigned u = __float_as_uint(f);
    return (ushort)((u + 0x7FFFu + ((u >> 16) & 1u)) >> 16);
}
__device__ __forceinline__ float bf2f(ushort h){
    return __uint_as_float(((unsigned)h) << 16);
}

using bf16x8 = __attribute__((ext_vector_type(8))) short;
using f32x16 = __attribute__((ext_vector_type(16))) float;

// ---------------------------------------------------------------------------
// K1: fused feature-transform + PQ GEMM (fp32 math) + weight-transpose tail.
// blocks [0,256): tile 64 rows x 128 cols; P fp32 [BN][64], Q bf16 [BN][64].
// blocks [256,280): Wf1 [192][256] -> Wf1T bf16 [256][192]
// blocks [280,296): Wf2 [256][128] -> Wf2T bf16 [128][256]
// ---------------------------------------------------------------------------
__global__ __launch_bounds__(256) void k_pq(
    const float* __restrict__ x,
    const float* __restrict__ W1, const float* __restrict__ b1,
    const float* __restrict__ g1, const float* __restrict__ be1,
    const float* __restrict__ W2,
    const float* __restrict__ Wf1, const float* __restrict__ Wf2,
    float* __restrict__ P, ushort* __restrict__ Qb,
    ushort* __restrict__ Wf1T, ushort* __restrict__ Wf2T)
{
    int t = threadIdx.x;
    int bid = blockIdx.x;
    if (bid >= 256) {
        if (bid < 280) {
            int base = (bid - 256) * 2048 + t * 8;
            #pragma unroll
            for (int j = 0; j < 8; ++j) {
                int e = base + j;              // e < 49152
                int n = e / 192, k = e % 192;
                Wf1T[e] = f2bf(Wf1[k*256 + n]);
            }
        } else {
            int base = (bid - 280) * 2048 + t * 8;
            #pragma unroll
            for (int j = 0; j < 8; ++j) {
                int e = base + j;              // e < 32768
                int n = e / 256, k = e % 256;
                Wf2T[e] = f2bf(Wf2[k*128 + n]);
            }
        }
        return;
    }

    __shared__ float F_s[64*66];    // 16.9 KB
    __shared__ float W_s[32*132];   // 16.9 KB

    int rb = bid * 64;

    // feat: 4 groups of 64 threads (lane=d), 16 rows each
    {
        int d = t & 63, g = t >> 6;
        float w0 = W1[d], w1 = W1[64+d], w2 = W1[128+d];
        float bb = b1[d], gg = g1[d], ee = be1[d];
        #pragma unroll 4
        for (int i = 0; i < 16; ++i) {
            int r = g*16 + i;
            const float* xp = &x[(rb + r)*3];
            float f = xp[0]*w0 + xp[1]*w1 + xp[2]*w2 + bb;
            f = leaky(f*gg + ee);
            F_s[r*66 + d] = f;
        }
    }

    int tx = t & 15, ty = t >> 4;   // 8 cols x 4 rows micro-tile
    float acc[4][8];
    #pragma unroll
    for (int i = 0; i < 4; ++i)
        #pragma unroll
        for (int j = 0; j < 8; ++j) acc[i][j] = 0.f;

    for (int k0 = 0; k0 < 64; k0 += 32) {
        __syncthreads();
        // stage W' 32 x 128 : W'[k][c] = W2[k + 64*(c>=64)][c&63]
        #pragma unroll
        for (int it = 0; it < 2; ++it) {
            int i2 = t + it*256;                 // 0..511
            int k = i2 >> 4, c8 = (i2 & 15) * 8;
            const float* src = &W2[(k0 + k + (c8 >= 64 ? 64 : 0))*64 + (c8 & 63)];
            *(float4*)&W_s[k*132 + c8]     = *(const float4*)src;
            *(float4*)&W_s[k*132 + c8 + 4] = *(const float4*)(src + 4);
        }
        __syncthreads();
        #pragma unroll 4
        for (int kk = 0; kk < 32; ++kk) {
            float a[4];
            #pragma unroll
            for (int i = 0; i < 4; ++i) a[i] = F_s[(ty*4 + i)*66 + k0 + kk];
            float4 wA = *(const float4*)&W_s[kk*132 + tx*8];
            float4 wB = *(const float4*)&W_s[kk*132 + tx*8 + 4];
            #pragma unroll
            for (int i = 0; i < 4; ++i) {
                acc[i][0] = fmaf(a[i], wA.x, acc[i][0]);
                acc[i][1] = fmaf(a[i], wA.y, acc[i][1]);
                acc[i][2] = fmaf(a[i], wA.z, acc[i][2]);
                acc[i][3] = fmaf(a[i], wA.w, acc[i][3]);
                acc[i][4] = fmaf(a[i], wB.x, acc[i][4]);
                acc[i][5] = fmaf(a[i], wB.y, acc[i][5]);
                acc[i][6] = fmaf(a[i], wB.z, acc[i][6]);
                acc[i][7] = fmaf(a[i], wB.w, acc[i][7]);
            }
        }
    }

    #pragma unroll
    for (int i = 0; i < 4; ++i) {
        int r = rb + ty*4 + i;
        if (tx < 8) {        // cols 0..63 -> P (fp32)
            *(float4*)&P[r*64 + tx*8]     = make_float4(acc[i][0], acc[i][1], acc[i][2], acc[i][3]);
            *(float4*)&P[r*64 + tx*8 + 4] = make_float4(acc[i][4], acc[i][5], acc[i][6], acc[i][7]);
        } else {             // cols 64..127 -> Q (bf16)
            union { ushort u[8]; uint4 v; } pk;
            #pragma unroll
            for (int j = 0; j < 8; ++j) pk.u[j] = f2bf(acc[i][j]);
            *(uint4*)&Qb[r*64 + (tx - 8)*8] = pk.v;
        }
    }
}

// ---------------------------------------------------------------------------
// K2: exact KNN, top-8 smallest d2, ties -> lower index (stable top_k).
// u64 keys (hi = float bits of clamped d2, lo = local index).
// Batcher sort-8 + bitonic min-merge per group of 8 candidates.
// Block: 1024 thr = 32 queries x 32 segments x 64 candidates.
// ---------------------------------------------------------------------------
#define CE64(a, b) { bool c_ = (b) < (a); unsigned long long mn_ = c_ ? (b) : (a); \
                     unsigned long long mx_ = c_ ? (a) : (b); (a) = mn_; (b) = mx_; }

__global__ __launch_bounds__(1024, 8) void k_knn(const float* __restrict__ x, int* __restrict__ idxo)
{
    __shared__ __align__(16) char smem[65536];
    float4*   sp  = (float4*)smem;               // 32 KB (scan phase)
    unsigned* khi = (unsigned*)smem;             // [8][1024] (merge phase)
    unsigned* klo = (unsigned*)(smem + 32768);

    int t = threadIdx.x;
    int b = blockIdx.x >> 6;
    int qbase = (blockIdx.x & 63) * 32;
    int q = t & 31, seg = t >> 5;

    for (int i = t; i < NN; i += 1024) {
        float a = x[(b*NN + i)*3 + 0];
        float c = x[(b*NN + i)*3 + 1];
        float e = x[(b*NN + i)*3 + 2];
        sp[i] = make_float4(a, c, e, a*a + c*c + e*e);
    }
    __syncthreads();

    float4 qv = sp[qbase + q];

    unsigned long long R[8];
    #pragma unroll
    for (int j = 0; j < 8; ++j) R[j] = 0xFFFFFFFFFFFFFFFFull;

    int m0 = seg * 64;
    #pragma unroll 2
    for (int g = 0; g < 8; ++g) {
        unsigned long long S[8];
        #pragma unroll
        for (int jj = 0; jj < 8; ++jj) {
            int m = m0 + g*8 + jj;
            float4 v = sp[m];
            float s = qv.x*v.x; s = fmaf(qv.y, v.y, s); s = fmaf(qv.z, v.z, s);
            float d2 = fmaf(-2.f, s, qv.w + v.w);
            // clamp: non-negative float bits are order-monotone; only the
            // self-point can go (tiny) negative by cancellation
            unsigned u = __float_as_uint(fmaxf(d2, 0.f));
            S[jj] = ((unsigned long long)u << 32) | (unsigned)m;
        }
        CE64(S[0],S[1]); CE64(S[2],S[3]); CE64(S[4],S[5]); CE64(S[6],S[7]);
        CE64(S[0],S[2]); CE64(S[1],S[3]); CE64(S[4],S[6]); CE64(S[5],S[7]);
        CE64(S[1],S[2]); CE64(S[5],S[6]);
        CE64(S[0],S[4]); CE64(S[1],S[5]); CE64(S[2],S[6]); CE64(S[3],S[7]);
        CE64(S[2],S[4]); CE64(S[3],S[5]);
        CE64(S[1],S[2]); CE64(S[3],S[4]); CE64(S[5],S[6]);
        #pragma unroll
        for (int j = 0; j < 8; ++j) {
            unsigned long long bb = S[7-j];
            R[j] = R[j] < bb ? R[j] : bb;
        }
        CE64(R[0],R[4]); CE64(R[1],R[5]); CE64(R[2],R[6]); CE64(R[3],R[7]);
        CE64(R[0],R[2]); CE64(R[1],R[3]); CE64(R[4],R[6]); CE64(R[5],R[7]);
        CE64(R[0],R[1]); CE64(R[2],R[3]); CE64(R[4],R[5]); CE64(R[6],R[7]);
    }

    __syncthreads();
    #pragma unroll
    for (int j = 0; j < 8; ++j) {
        khi[j*1024 + t] = (unsigned)(R[j] >> 32);
        klo[j*1024 + t] = (unsigned)R[j];
    }

    for (int L = 32; L >= 2; L >>= 1) {
        __syncthreads();
        unsigned long long A[8], Bv[8];
        int p = t >> 5;
        bool active = (p < (L >> 1));
        if (active) {
            int rowA = (2*p)*32 + q, rowB = (2*p + 1)*32 + q;
            #pragma unroll
            for (int j = 0; j < 8; ++j) {
                A[j]  = ((unsigned long long)khi[j*1024 + rowA] << 32) | klo[j*1024 + rowA];
                Bv[j] = ((unsigned long long)khi[j*1024 + rowB] << 32) | klo[j*1024 + rowB];
            }
        }
        __syncthreads();
        if (active) {
            unsigned long long C[8];
            #pragma unroll
            for (int j = 0; j < 8; ++j) {
                unsigned long long bb = Bv[7-j];
                C[j] = A[j] < bb ? A[j] : bb;
            }
            CE64(C[0],C[4]); CE64(C[1],C[5]); CE64(C[2],C[6]); CE64(C[3],C[7]);
            CE64(C[0],C[2]); CE64(C[1],C[3]); CE64(C[4],C[6]); CE64(C[5],C[7]);
            CE64(C[0],C[1]); CE64(C[2],C[3]); CE64(C[4],C[5]); CE64(C[6],C[7]);
            if (L > 2) {
                int rowO = p*32 + q;
                #pragma unroll
                for (int j = 0; j < 8; ++j) {
                    khi[j*1024 + rowO] = (unsigned)(C[j] >> 32);
                    klo[j*1024 + rowO] = (unsigned)C[j];
                }
            } else {
                #pragma unroll
                for (int j = 0; j < 8; ++j)
                    idxo[(b*NN + qbase + q)*KNB + j] = b*NN + (int)(C[j] & 0xFFFFFFFFu);
            }
        }
    }
}

// ---------------------------------------------------------------------------
// K3: mega-fusion: suppressor(fw) + gather-max edge conv + multi(A) build
//     + h1 MFMA + h2 MFMA + Wf3 reduction + residual out.
// Block = 64 rows, 256 threads (4 waves). All intermediates stay in LDS.
// LDS overlay (60.9 KB total):
//   [0,25600)      A_s   ushort[64][200]   (phase A..h1 MFMA)
//   [25600,62464)  B_s   ushort[256][72]   (h1 B-tiles)
//   [0,33792)      h1_s  ushort[64][264]   (after h1 MFMA; overwrites A_s+B_s head)
//   [40960,59392)  B2_s  ushort[128][72]   (h2 B-tiles)
//   [59392,60928)  pd    float[64][2][3]   (epilogue partials)
// Wave w: row-group rg=w>>1 (rows rg*32..+31 for MFMA), col-half (w&1).
// ---------------------------------------------------------------------------
__global__ __launch_bounds__(256) void k_fuse(
    const float* __restrict__ x,
    const float* __restrict__ P, const ushort* __restrict__ Qb,
    const int* __restrict__ idx,
    const float* __restrict__ Ws1, const float* __restrict__ bs1,
    const float* __restrict__ Ws2, const float* __restrict__ bs2,
    const float* __restrict__ b2, const float* __restrict__ g2,
    const float* __restrict__ be2,
    const ushort* __restrict__ Wf1T, const float* __restrict__ bf1,
    const float* __restrict__ gf1, const float* __restrict__ bef1,
    const ushort* __restrict__ Wf2T, const float* __restrict__ bf2,
    const float* __restrict__ gf2, const float* __restrict__ bef2,
    const float* __restrict__ Wf3, const float* __restrict__ bf3,
    float* __restrict__ out)
{
    __shared__ __align__(16) char smem[60928];
    ushort* A_s  = (ushort*)smem;             // [64][200]
    ushort* B_s  = (ushort*)(smem + 25600);   // [256][72]
    ushort* h1_s = (ushort*)smem;             // [64][264]
    ushort* B2_s = (ushort*)(smem + 40960);   // [128][72]
    float*  pd   = (float*) (smem + 59392);   // [64][2][3]

    int t = threadIdx.x, w = t >> 6, lane = t & 63;
    int rb = blockIdx.x * 64;

    // ---- phase A: fw + gather-max -> A_s (wave w: rows w*16..w*16+15) ----
    {
        float ws1a = Ws1[lane], ws1b = Ws1[64+lane], ws1c = Ws1[128+lane];
        float bs1v = bs1[lane];
        float ws2a = Ws2[lane*3+0], ws2b = Ws2[lane*3+1], ws2c = Ws2[lane*3+2];
        float bs20 = bs2[0], bs21 = bs2[1], bs22 = bs2[2];
        float g2v = g2[lane], be2v = be2[lane], b2v = b2[lane];
        for (int i = 0; i < 16; ++i) {
            int r = w*16 + i, p = rb + r;
            float x0 = x[p*3+0], x1 = x[p*3+1], x2 = x[p*3+2];
            float h = fmaxf(fmaf(x2, ws1c, fmaf(x1, ws1b, fmaf(x0, ws1a, bs1v))), 0.f);
            float s0 = h*ws2a, s1 = h*ws2b, s2 = h*ws2c;
            #pragma unroll
            for (int off = 32; off; off >>= 1) {
                s0 += __shfl_xor(s0, off, 64);
                s1 += __shfl_xor(s1, off, 64);
                s2 += __shfl_xor(s2, off, 64);
            }
            float fw0 = 1.f/(1.f + expf(-(s0 + bs20)));
            float fw1 = 1.f/(1.f + expf(-(s1 + bs21)));
            float fw2 = 1.f/(1.f + expf(-(s2 + bs22)));
            float Pv = P[p*64 + lane] + b2v;
            float mx = -1e30f;
            #pragma unroll
            for (int j = 0; j < KNB; ++j) {
                int nb = idx[p*KNB + j];
                float qv = bf2f(Qb[nb*64 + lane]);
                mx = fmaxf(mx, leaky((Pv + qv)*g2v + be2v));
            }
            A_s[r*200 + lane]       = f2bf(mx * fw0);
            A_s[r*200 + 64 + lane]  = f2bf(mx * fw1);
            A_s[r*200 + 128 + lane] = f2bf(mx * fw2);
        }
    }

    // ---- h1 = leaky((A @ Wf1 + bf1)*gf1 + bef1), N=256 full width ----
    int rg = w >> 1;                 // row-group 0/1
    int nh = (w & 1) * 128;          // h1 col-half
    int l31 = lane & 31, kb = (lane >> 5) * 8;
    int row = rg*32 + l31;

    f32x16 acc[4];
    #pragma unroll
    for (int n2 = 0; n2 < 4; ++n2)
        #pragma unroll
        for (int i = 0; i < 16; ++i) acc[n2][i] = 0.f;

    for (int k0 = 0; k0 < 192; k0 += 64) {
        __syncthreads();
        #pragma unroll
        for (int it = 0; it < 8; ++it) {
            int i = t + it*256;              // 0..2047
            int n = i >> 3, kq = (i & 7)*8;
            *(uint4*)&B_s[n*72 + kq] = *(const uint4*)&Wf1T[n*192 + k0 + kq];
        }
        __syncthreads();
        #pragma unroll
        for (int s = 0; s < 4; ++s) {
            bf16x8 a = *(const bf16x8*)&A_s[row*200 + k0 + s*16 + kb];
            #pragma unroll
            for (int n2 = 0; n2 < 4; ++n2) {
                bf16x8 b = *(const bf16x8*)&B_s[(nh + n2*32 + l31)*72 + s*16 + kb];
                acc[n2] = __builtin_amdgcn_mfma_f32_32x32x16_bf16(a, b, acc[n2], 0, 0, 0);
            }
        }
    }
    __syncthreads();   // A_s/B_s dead; safe to overwrite with h1_s

    #pragma unroll
    for (int n2 = 0; n2 < 4; ++n2) {
        int c = nh + n2*32 + l31;
        float bv = bf1[c], gv = gf1[c], ev = bef1[c];
        #pragma unroll
        for (int r16 = 0; r16 < 16; ++r16) {
            int rr = (r16 & 3) + 8*(r16 >> 2) + 4*(lane >> 5);
            float v = leaky((acc[n2][r16] + bv)*gv + ev);
            h1_s[(rg*32 + rr)*264 + c] = f2bf(v);
        }
    }

    // ---- h2 = leaky((h1 @ Wf2 + bf2)*gf2 + bef2), N=128; wave col-half 64 ----
    int ch = (w & 1) * 64;
    f32x16 acc2[2];
    #pragma unroll
    for (int n2 = 0; n2 < 2; ++n2)
        #pragma unroll
        for (int i = 0; i < 16; ++i) acc2[n2][i] = 0.f;

    for (int k0 = 0; k0 < 256; k0 += 64) {
        __syncthreads();
        #pragma unroll
        for (int it = 0; it < 4; ++it) {
            int i = t + it*256;              // 0..1023
            int n = i >> 3, kq = (i & 7)*8;
            *(uint4*)&B2_s[n*72 + kq] = *(const uint4*)&Wf2T[n*256 + k0 + kq];
        }
        __syncthreads();
        #pragma unroll
        for (int s = 0; s < 4; ++s) {
            bf16x8 a = *(const bf16x8*)&h1_s[row*264 + k0 + s*16 + kb];
            #pragma unroll
            for (int n2 = 0; n2 < 2; ++n2) {
                bf16x8 b = *(const bf16x8*)&B2_s[(ch + n2*32 + l31)*72 + s*16 + kb];
                acc2[n2] = __builtin_amdgcn_mfma_f32_32x32x16_bf16(a, b, acc2[n2], 0, 0, 0);
            }
        }
    }

    // ---- epilogue: per-row delta partials over this wave's 64 cols ----
    float bv[2], gv[2], ev[2], w3[2][3];
    #pragma unroll
    for (int n2 = 0; n2 < 2; ++n2) {
        int c = ch + n2*32 + l31;
        bv[n2] = bf2[c]; gv[n2] = gf2[c]; ev[n2] = bef2[c];
        #pragma unroll
        for (int l = 0; l < 3; ++l) w3[n2][l] = Wf3[c*3 + l];
    }
    __syncthreads();   // B2_s reads done; pd region free
    #pragma unroll
    for (int r16 = 0; r16 < 16; ++r16) {
        float d0 = 0.f, d1 = 0.f, d2 = 0.f;
        #pragma unroll
        for (int n2 = 0; n2 < 2; ++n2) {
            float v = leaky((acc2[n2][r16] + bv[n2])*gv[n2] + ev[n2]);
            d0 = fmaf(v, w3[n2][0], d0);
            d1 = fmaf(v, w3[n2][1], d1);
            d2 = fmaf(v, w3[n2][2], d2);
        }
        #pragma unroll
        for (int off = 16; off; off >>= 1) {   // reduce within 32-lane half
            d0 += __shfl_xor(d0, off, 64);
            d1 += __shfl_xor(d1, off, 64);
            d2 += __shfl_xor(d2, off, 64);
        }
        int rr = rg*32 + (r16 & 3) + 8*(r16 >> 2) + 4*(lane >> 5);
        if (l31 < 3) {
            float dl = (l31 == 0) ? d0 : (l31 == 1 ? d1 : d2);
            pd[(rr*2 + (w & 1))*3 + l31] = dl;
        }
    }
    __syncthreads();

    if (t < 192) {
        int r = t / 3, l = t - r*3;
        float delta = pd[(r*2 + 0)*3 + l] + pd[(r*2 + 1)*3 + l] + bf3[l];
        out[(rb + r)*3 + l] = x[(rb + r)*3 + l] + 0.1f*delta;
    }
}

// ---------------------------------------------------------------------------
extern "C" void kernel_launch(void* const* d_in, const int* in_sizes, int n_in,
                              void* d_out, int out_size, void* d_ws, size_t ws_size,
                              hipStream_t stream)
{
    const float* x    = (const float*)d_in[0];
    const float* W1   = (const float*)d_in[1];
    const float* b1   = (const float*)d_in[2];
    const float* g1   = (const float*)d_in[3];
    const float* be1  = (const float*)d_in[4];
    const float* W2   = (const float*)d_in[5];
    const float* b2   = (const float*)d_in[6];
    const float* g2   = (const float*)d_in[7];
    const float* be2  = (const float*)d_in[8];
    const float* Ws1  = (const float*)d_in[9];
    const float* bs1  = (const float*)d_in[10];
    const float* Ws2  = (const float*)d_in[11];
    const float* bs2  = (const float*)d_in[12];
    const float* Wf1  = (const float*)d_in[13];
    const float* bf1  = (const float*)d_in[14];
    const float* gf1  = (const float*)d_in[15];
    const float* bef1 = (const float*)d_in[16];
    const float* Wf2  = (const float*)d_in[17];
    const float* bf2  = (const float*)d_in[18];
    const float* gf2  = (const float*)d_in[19];
    const float* bef2 = (const float*)d_in[20];
    const float* Wf3  = (const float*)d_in[21];
    const float* bf3  = (const float*)d_in[22];
    float* out = (float*)d_out;

    char* ws = (char*)d_ws;
    int*    idx   = (int*)   (ws + 0);             // 512 KB
    ushort* Wf1T  = (ushort*)(ws + (1u << 20));    // 96 KB
    ushort* Wf2T  = (ushort*)(ws + (1u << 20) + (512u << 10)); // 64 KB
    float*  P     = (float*) (ws + (2u  << 20));   // 4 MB   [BN][64] fp32
    ushort* Qb    = (ushort*)(ws + (6u  << 20));   // 2 MB   [BN][64] bf16

    k_pq<<<296, 256, 0, stream>>>(x, W1, b1, g1, be1, W2, Wf1, Wf2, P, Qb, Wf1T, Wf2T);
    k_knn<<<BB*64, 1024, 0, stream>>>(x, idx);
    k_fuse<<<BN/64, 256, 0, stream>>>(x, P, Qb, idx, Ws1, bs1, Ws2, bs2, b2, g2, be2,
                                      Wf1T, bf1, gf1, bef1, Wf2T, bf2, gf2, bef2,
                                      Wf3, bf3, out);
}

// Round 8
// 163.177 us; speedup vs baseline: 1.5542x; 1.0546x over previous
//
#include <hip/hip_runtime.h>
#include <hip/hip_bf16.h>
#include <math.h>

// Problem constants: B=8, N=2048, C_IN=3, D=64, K=8, LEVELS=3, H1=256, H2=128
#define BB   8
#define NN   2048
#define BN   16384   // B*N
#define KNB  8

__device__ __forceinline__ float leaky(float v){ return v > 0.f ? v : 0.2f*v; }

// RNE float->bf16 bits (finite inputs), matches __float2bfloat16 rounding
__device__ __forceinline__ ushort f2bf(float f){
    unsigned u = __float_as_uint(f);
    return (ushort)((u + 0x7FFFu + ((u >> 16) & 1u)) >> 16);
}
__device__ __forceinline__ float bf2f(ushort h){
    return __uint_as_float(((unsigned)h) << 16);
}

using bf16x8 = __attribute__((ext_vector_type(8))) short;
using f32x16 = __attribute__((ext_vector_type(16))) float;

// ---------------------------------------------------------------------------
// K1: fused feature-transform + PQ GEMM (fp32 math) + weight-transpose tail.
// blocks [0,256): tile 64 rows x 128 cols; P fp32 [BN][64], Q bf16 [BN][64].
// blocks [256,280): Wf1 [192][256] -> Wf1T bf16 [256][192]
// blocks [280,296): Wf2 [256][128] -> Wf2T bf16 [128][256]
// ---------------------------------------------------------------------------
__global__ __launch_bounds__(256) void k_pq(
    const float* __restrict__ x,
    const float* __restrict__ W1, const float* __restrict__ b1,
    const float* __restrict__ g1, const float* __restrict__ be1,
    const float* __restrict__ W2,
    const float* __restrict__ Wf1, const float* __restrict__ Wf2,
    float* __restrict__ P, ushort* __restrict__ Qb,
    ushort* __restrict__ Wf1T, ushort* __restrict__ Wf2T)
{
    int t = threadIdx.x;
    int bid = blockIdx.x;
    if (bid >= 256) {
        if (bid < 280) {
            int base = (bid - 256) * 2048 + t * 8;
            #pragma unroll
            for (int j = 0; j < 8; ++j) {
                int e = base + j;              // e < 49152
                int n = e / 192, k = e % 192;
                Wf1T[e] = f2bf(Wf1[k*256 + n]);
            }
        } else {
            int base = (bid - 280) * 2048 + t * 8;
            #pragma unroll
            for (int j = 0; j < 8; ++j) {
                int e = base + j;              // e < 32768
                int n = e / 256, k = e % 256;
                Wf2T[e] = f2bf(Wf2[k*128 + n]);
            }
        }
        return;
    }

    __shared__ float F_s[64*66];    // 16.9 KB
    __shared__ float W_s[32*132];   // 16.9 KB

    int rb = bid * 64;

    // feat: 4 groups of 64 threads (lane=d), 16 rows each
    {
        int d = t & 63, g = t >> 6;
        float w0 = W1[d], w1 = W1[64+d], w2 = W1[128+d];
        float bb = b1[d], gg = g1[d], ee = be1[d];
        #pragma unroll 4
        for (int i = 0; i < 16; ++i) {
            int r = g*16 + i;
            const float* xp = &x[(rb + r)*3];
            float f = xp[0]*w0 + xp[1]*w1 + xp[2]*w2 + bb;
            f = leaky(f*gg + ee);
            F_s[r*66 + d] = f;
        }
    }

    int tx = t & 15, ty = t >> 4;   // 8 cols x 4 rows micro-tile
    float acc[4][8];
    #pragma unroll
    for (int i = 0; i < 4; ++i)
        #pragma unroll
        for (int j = 0; j < 8; ++j) acc[i][j] = 0.f;

    for (int k0 = 0; k0 < 64; k0 += 32) {
        __syncthreads();
        // stage W' 32 x 128 : W'[k][c] = W2[k + 64*(c>=64)][c&63]
        #pragma unroll
        for (int it = 0; it < 2; ++it) {
            int i2 = t + it*256;                 // 0..511
            int k = i2 >> 4, c8 = (i2 & 15) * 8;
            const float* src = &W2[(k0 + k + (c8 >= 64 ? 64 : 0))*64 + (c8 & 63)];
            *(float4*)&W_s[k*132 + c8]     = *(const float4*)src;
            *(float4*)&W_s[k*132 + c8 + 4] = *(const float4*)(src + 4);
        }
        __syncthreads();
        #pragma unroll 4
        for (int kk = 0; kk < 32; ++kk) {
            float a[4];
            #pragma unroll
            for (int i = 0; i < 4; ++i) a[i] = F_s[(ty*4 + i)*66 + k0 + kk];
            float4 wA = *(const float4*)&W_s[kk*132 + tx*8];
            float4 wB = *(const float4*)&W_s[kk*132 + tx*8 + 4];
            #pragma unroll
            for (int i = 0; i < 4; ++i) {
                acc[i][0] = fmaf(a[i], wA.x, acc[i][0]);
                acc[i][1] = fmaf(a[i], wA.y, acc[i][1]);
                acc[i][2] = fmaf(a[i], wA.z, acc[i][2]);
                acc[i][3] = fmaf(a[i], wA.w, acc[i][3]);
                acc[i][4] = fmaf(a[i], wB.x, acc[i][4]);
                acc[i][5] = fmaf(a[i], wB.y, acc[i][5]);
                acc[i][6] = fmaf(a[i], wB.z, acc[i][6]);
                acc[i][7] = fmaf(a[i], wB.w, acc[i][7]);
            }
        }
    }

    #pragma unroll
    for (int i = 0; i < 4; ++i) {
        int r = rb + ty*4 + i;
        if (tx < 8) {        // cols 0..63 -> P (fp32)
            *(float4*)&P[r*64 + tx*8]     = make_float4(acc[i][0], acc[i][1], acc[i][2], acc[i][3]);
            *(float4*)&P[r*64 + tx*8 + 4] = make_float4(acc[i][4], acc[i][5], acc[i][6], acc[i][7]);
        } else {             // cols 64..127 -> Q (bf16)
            union { ushort u[8]; uint4 v; } pk;
            #pragma unroll
            for (int j = 0; j < 8; ++j) pk.u[j] = f2bf(acc[i][j]);
            *(uint4*)&Qb[r*64 + (tx - 8)*8] = pk.v;
        }
    }
}

// ---------------------------------------------------------------------------
// K2: exact KNN via value/index decomposition (output = SET of 8 nearest,
// order-free — downstream is a max-pool; set == stable-top-k set).
// Phase A: value-only top-8 scan. CE = v_min_f32+v_max_f32 (2 inst).
//   Batcher sort-8 + bitonic min-merge per group of 8 candidates.
// Phase A2: intra-wave merge (shfl_xor 32) + 4-level LDS tree -> v8[q]
//   (exact 8th-smallest clamped d2 per query).
// Phase B: index recovery rescan: identical d2 expression; ballot-rank
//   collection; all d2 < v8 plus lowest-index ties at v8.
// Block: 1024 thr = 32 queries x 32 segments x 64 candidates.
// ---------------------------------------------------------------------------
#define CEF(a, b) { float mn_ = fminf(a,b), mx_ = fmaxf(a,b); (a) = mn_; (b) = mx_; }

__global__ __launch_bounds__(1024, 8) void k_knn(const float* __restrict__ x, int* __restrict__ idxo)
{
    __shared__ __align__(16) char smem[50560];
    float4* sp    = (float4*)smem;                // [2048] 32 KB
    float*  mg    = (float*) (smem + 32768);      // [16][32][8] 16 KB
    float*  v8buf = (float*) (smem + 49152);      // [32]
    int*    eqbuf = (int*)   (smem + 49280);      // [32][8]
    int*    c1buf = (int*)   (smem + 50304);      // [32]

    int t = threadIdx.x;
    int b = blockIdx.x >> 6;
    int qbase = (blockIdx.x & 63) * 32;
    int q = t & 31, seg = t >> 5;
    int w = t >> 6, lane = t & 63;

    for (int i = t; i < NN; i += 1024) {
        float a = x[(b*NN + i)*3 + 0];
        float c = x[(b*NN + i)*3 + 1];
        float e = x[(b*NN + i)*3 + 2];
        sp[i] = make_float4(a, c, e, a*a + c*c + e*e);
    }
    __syncthreads();

    // ---- Phase A: value-only top-8 over this lane's 64 candidates ----
    float4 qv = sp[qbase + q];
    float R[8];
    #pragma unroll
    for (int j = 0; j < 8; ++j) R[j] = 1e30f;

    int m0 = seg * 64;
    #pragma unroll 2
    for (int g = 0; g < 8; ++g) {
        float S[8];
        #pragma unroll
        for (int jj = 0; jj < 8; ++jj) {
            int m = m0 + g*8 + jj;
            float4 v = sp[m];
            float s = qv.x*v.x; s = fmaf(qv.y, v.y, s); s = fmaf(qv.z, v.z, s);
            float d2 = fmaf(-2.f, s, qv.w + v.w);
            S[jj] = fmaxf(d2, 0.f);
        }
        // Batcher odd-even mergesort, 8 elems, 19 CEs (ascending)
        CEF(S[0],S[1]); CEF(S[2],S[3]); CEF(S[4],S[5]); CEF(S[6],S[7]);
        CEF(S[0],S[2]); CEF(S[1],S[3]); CEF(S[4],S[6]); CEF(S[5],S[7]);
        CEF(S[1],S[2]); CEF(S[5],S[6]);
        CEF(S[0],S[4]); CEF(S[1],S[5]); CEF(S[2],S[6]); CEF(S[3],S[7]);
        CEF(S[2],S[4]); CEF(S[3],S[5]);
        CEF(S[1],S[2]); CEF(S[3],S[4]); CEF(S[5],S[6]);
        // keep 8 smallest of R ∪ S
        #pragma unroll
        for (int j = 0; j < 8; ++j) R[j] = fminf(R[j], S[7-j]);
        CEF(R[0],R[4]); CEF(R[1],R[5]); CEF(R[2],R[6]); CEF(R[3],R[7]);
        CEF(R[0],R[2]); CEF(R[1],R[3]); CEF(R[4],R[6]); CEF(R[5],R[7]);
        CEF(R[0],R[1]); CEF(R[2],R[3]); CEF(R[4],R[5]); CEF(R[6],R[7]);
    }

    // ---- Phase A2a: intra-wave merge (seg 2w with seg 2w+1) ----
    {
        float Rp[8];
        #pragma unroll
        for (int j = 0; j < 8; ++j) Rp[j] = __shfl_xor(R[j], 32, 64);
        float C[8];
        #pragma unroll
        for (int j = 0; j < 8; ++j) C[j] = fminf(R[j], Rp[7-j]);
        CEF(C[0],C[4]); CEF(C[1],C[5]); CEF(C[2],C[6]); CEF(C[3],C[7]);
        CEF(C[0],C[2]); CEF(C[1],C[3]); CEF(C[4],C[6]); CEF(C[5],C[7]);
        CEF(C[0],C[1]); CEF(C[2],C[3]); CEF(C[4],C[5]); CEF(C[6],C[7]);
        if (lane < 32) {
            #pragma unroll
            for (int j = 0; j < 8; ++j) mg[(w*32 + lane)*8 + j] = C[j];
        }
    }

    // ---- Phase A2b: 4-level tree 16 -> 1, value-only ----
    #pragma unroll
    for (int lvl = 0; lvl < 4; ++lvl) {
        int P = 8 >> lvl;          // pairs per query
        int sh = 3 - lvl;
        bool active = (t < 32*P);
        float C[8];
        int qq = 0, p = 0;
        __syncthreads();
        if (active) {
            qq = t >> sh; p = t & (P - 1);
            float A[8], Bv[8];
            #pragma unroll
            for (int j = 0; j < 8; ++j) {
                A[j]  = mg[((2*p)*32 + qq)*8 + j];
                Bv[j] = mg[((2*p + 1)*32 + qq)*8 + j];
            }
            #pragma unroll
            for (int j = 0; j < 8; ++j) C[j] = fminf(A[j], Bv[7-j]);
            CEF(C[0],C[4]); CEF(C[1],C[5]); CEF(C[2],C[6]); CEF(C[3],C[7]);
            CEF(C[0],C[2]); CEF(C[1],C[3]); CEF(C[4],C[6]); CEF(C[5],C[7]);
            CEF(C[0],C[1]); CEF(C[2],C[3]); CEF(C[4],C[5]); CEF(C[6],C[7]);
        }
        __syncthreads();
        if (active) {
            if (P > 1) {
                #pragma unroll
                for (int j = 0; j < 8; ++j) mg[(p*32 + qq)*8 + j] = C[j];
            } else {
                v8buf[qq] = C[7];
            }
        }
    }
    __syncthreads();

    // ---- Phase B: index recovery. wave w handles queries 2w, 2w+1 ----
    #pragma unroll
    for (int u = 0; u < 2; ++u) {
        int qq = w*2 + u;
        float4 qv2 = sp[qbase + qq];
        float v8 = v8buf[qq];
        int cLT = 0, cEQ = 0;
        unsigned long long below = (1ull << lane) - 1ull;
        for (int g = 0; g < 32; ++g) {
            int m = g*64 + lane;
            float4 v = sp[m];
            float s = qv2.x*v.x; s = fmaf(qv2.y, v.y, s); s = fmaf(qv2.z, v.z, s);
            float d2 = fmaf(-2.f, s, qv2.w + v.w);
            d2 = fmaxf(d2, 0.f);
            bool lt = d2 < v8, eq = d2 == v8;
            unsigned long long mlt = __ballot(lt);
            unsigned long long meq = __ballot(eq);
            if (mlt | meq) {
                if (lt) {
                    int r = cLT + __popcll(mlt & below);
                    if (r < 8) idxo[(b*NN + qbase + qq)*KNB + r] = b*NN + m;
                } else if (eq) {
                    int r = cEQ + __popcll(meq & below);
                    if (r < 8) eqbuf[qq*8 + r] = m;
                }
                cLT += (int)__popcll(mlt);
                cEQ += (int)__popcll(meq);
            }
        }
        if (lane == 0) c1buf[qq] = cLT < 8 ? cLT : 8;
    }
    __syncthreads();

    if (t < 256) {
        int qq = t >> 3, j = t & 7;
        int c1 = c1buf[qq];
        if (j >= c1)
            idxo[(b*NN + qbase + qq)*KNB + j] = b*NN + eqbuf[qq*8 + (j - c1)];
    }
}

// ---------------------------------------------------------------------------
// K3: mega-fusion: suppressor(fw) + gather-max edge conv + multi(A) build
//     + h1 MFMA + h2 MFMA + Wf3 reduction + residual out.
// Block = 64 rows, 256 threads (4 waves). All intermediates stay in LDS.
// ---------------------------------------------------------------------------
__global__ __launch_bounds__(256) void k_fuse(
    const float* __restrict__ x,
    const float* __restrict__ P, const ushort* __restrict__ Qb,
    const int* __restrict__ idx,
    const float* __restrict__ Ws1, const float* __restrict__ bs1,
    const float* __restrict__ Ws2, const float* __restrict__ bs2,
    const float* __restrict__ b2, const float* __restrict__ g2,
    const float* __restrict__ be2,
    const ushort* __restrict__ Wf1T, const float* __restrict__ bf1,
    const float* __restrict__ gf1, const float* __restrict__ bef1,
    const ushort* __restrict__ Wf2T, const float* __restrict__ bf2,
    const float* __restrict__ gf2, const float* __restrict__ bef2,
    const float* __restrict__ Wf3, const float* __restrict__ bf3,
    float* __restrict__ out)
{
    __shared__ __align__(16) char smem[60928];
    ushort* A_s  = (ushort*)smem;             // [64][200]
    ushort* B_s  = (ushort*)(smem + 25600);   // [256][72]
    ushort* h1_s = (ushort*)smem;             // [64][264]
    ushort* B2_s = (ushort*)(smem + 40960);   // [128][72]
    float*  pd   = (float*) (smem + 59392);   // [64][2][3]

    int t = threadIdx.x, w = t >> 6, lane = t & 63;
    int rb = blockIdx.x * 64;

    // ---- phase A: fw + gather-max -> A_s (wave w: rows w*16..w*16+15) ----
    {
        float ws1a = Ws1[lane], ws1b = Ws1[64+lane], ws1c = Ws1[128+lane];
        float bs1v = bs1[lane];
        float ws2a = Ws2[lane*3+0], ws2b = Ws2[lane*3+1], ws2c = Ws2[lane*3+2];
        float bs20 = bs2[0], bs21 = bs2[1], bs22 = bs2[2];
        float g2v = g2[lane], be2v = be2[lane], b2v = b2[lane];
        for (int i = 0; i < 16; ++i) {
            int r = w*16 + i, p = rb + r;
            float x0 = x[p*3+0], x1 = x[p*3+1], x2 = x[p*3+2];
            float h = fmaxf(fmaf(x2, ws1c, fmaf(x1, ws1b, fmaf(x0, ws1a, bs1v))), 0.f);
            float s0 = h*ws2a, s1 = h*ws2b, s2 = h*ws2c;
            #pragma unroll
            for (int off = 32; off; off >>= 1) {
                s0 += __shfl_xor(s0, off, 64);
                s1 += __shfl_xor(s1, off, 64);
                s2 += __shfl_xor(s2, off, 64);
            }
            float fw0 = 1.f/(1.f + expf(-(s0 + bs20)));
            float fw1 = 1.f/(1.f + expf(-(s1 + bs21)));
            float fw2 = 1.f/(1.f + expf(-(s2 + bs22)));
            float Pv = P[p*64 + lane] + b2v;
            float mx = -1e30f;
            #pragma unroll
            for (int j = 0; j < KNB; ++j) {
                int nb = idx[p*KNB + j];
                float qv = bf2f(Qb[nb*64 + lane]);
                mx = fmaxf(mx, leaky((Pv + qv)*g2v + be2v));
            }
            A_s[r*200 + lane]       = f2bf(mx * fw0);
            A_s[r*200 + 64 + lane]  = f2bf(mx * fw1);
            A_s[r*200 + 128 + lane] = f2bf(mx * fw2);
        }
    }

    // ---- h1 = leaky((A @ Wf1 + bf1)*gf1 + bef1), N=256 full width ----
    int rg = w >> 1;                 // row-group 0/1
    int nh = (w & 1) * 128;          // h1 col-half
    int l31 = lane & 31, kb = (lane >> 5) * 8;
    int row = rg*32 + l31;

    f32x16 acc[4];
    #pragma unroll
    for (int n2 = 0; n2 < 4; ++n2)
        #pragma unroll
        for (int i = 0; i < 16; ++i) acc[n2][i] = 0.f;

    for (int k0 = 0; k0 < 192; k0 += 64) {
        __syncthreads();
        #pragma unroll
        for (int it = 0; it < 8; ++it) {
            int i = t + it*256;              // 0..2047
            int n = i >> 3, kq = (i & 7)*8;
            *(uint4*)&B_s[n*72 + kq] = *(const uint4*)&Wf1T[n*192 + k0 + kq];
        }
        __syncthreads();
        #pragma unroll
        for (int s = 0; s < 4; ++s) {
            bf16x8 a = *(const bf16x8*)&A_s[row*200 + k0 + s*16 + kb];
            #pragma unroll
            for (int n2 = 0; n2 < 4; ++n2) {
                bf16x8 b = *(const bf16x8*)&B_s[(nh + n2*32 + l31)*72 + s*16 + kb];
                acc[n2] = __builtin_amdgcn_mfma_f32_32x32x16_bf16(a, b, acc[n2], 0, 0, 0);
            }
        }
    }
    __syncthreads();   // A_s/B_s dead; safe to overwrite with h1_s

    #pragma unroll
    for (int n2 = 0; n2 < 4; ++n2) {
        int c = nh + n2*32 + l31;
        float bv = bf1[c], gv = gf1[c], ev = bef1[c];
        #pragma unroll
        for (int r16 = 0; r16 < 16; ++r16) {
            int rr = (r16 & 3) + 8*(r16 >> 2) + 4*(lane >> 5);
            float v = leaky((acc[n2][r16] + bv)*gv + ev);
            h1_s[(rg*32 + rr)*264 + c] = f2bf(v);
        }
    }

    // ---- h2 = leaky((h1 @ Wf2 + bf2)*gf2 + bef2), N=128; wave col-half 64 ----
    int ch = (w & 1) * 64;
    f32x16 acc2[2];
    #pragma unroll
    for (int n2 = 0; n2 < 2; ++n2)
        #pragma unroll
        for (int i = 0; i < 16; ++i) acc2[n2][i] = 0.f;

    for (int k0 = 0; k0 < 256; k0 += 64) {
        __syncthreads();
        #pragma unroll
        for (int it = 0; it < 4; ++it) {
            int i = t + it*256;              // 0..1023
            int n = i >> 3, kq = (i & 7)*8;
            *(uint4*)&B2_s[n*72 + kq] = *(const uint4*)&Wf2T[n*256 + k0 + kq];
        }
        __syncthreads();
        #pragma unroll
        for (int s = 0; s < 4; ++s) {
            bf16x8 a = *(const bf16x8*)&h1_s[row*264 + k0 + s*16 + kb];
            #pragma unroll
            for (int n2 = 0; n2 < 2; ++n2) {
                bf16x8 b = *(const bf16x8*)&B2_s[(ch + n2*32 + l31)*72 + s*16 + kb];
                acc2[n2] = __builtin_amdgcn_mfma_f32_32x32x16_bf16(a, b, acc2[n2], 0, 0, 0);
            }
        }
    }

    // ---- epilogue: per-row delta partials over this wave's 64 cols ----
    float bv[2], gv[2], ev[2], w3[2][3];
    #pragma unroll
    for (int n2 = 0; n2 < 2; ++n2) {
        int c = ch + n2*32 + l31;
        bv[n2] = bf2[c]; gv[n2] = gf2[c]; ev[n2] = bef2[c];
        #pragma unroll
        for (int l = 0; l < 3; ++l) w3[n2][l] = Wf3[c*3 + l];
    }
    __syncthreads();   // B2_s reads done; pd region free
    #pragma unroll
    for (int r16 = 0; r16 < 16; ++r16) {
        float d0 = 0.f, d1 = 0.f, d2 = 0.f;
        #pragma unroll
        for (int n2 = 0; n2 < 2; ++n2) {
            float v = leaky((acc2[n2][r16] + bv[n2])*gv[n2] + ev[n2]);
            d0 = fmaf(v, w3[n2][0], d0);
            d1 = fmaf(v, w3[n2][1], d1);
            d2 = fmaf(v, w3[n2][2], d2);
        }
        #pragma unroll
        for (int off = 16; off; off >>= 1) {   // reduce within 32-lane half
            d0 += __shfl_xor(d0, off, 64);
            d1 += __shfl_xor(d1, off, 64);
            d2 += __shfl_xor(d2, off, 64);
        }
        int rr = rg*32 + (r16 & 3) + 8*(r16 >> 2) + 4*(lane >> 5);
        if (l31 < 3) {
            float dl = (l31 == 0) ? d0 : (l31 == 1 ? d1 : d2);
            pd[(rr*2 + (w & 1))*3 + l31] = dl;
        }
    }
    __syncthreads();

    if (t < 192) {
        int r = t / 3, l = t - r*3;
        float delta = pd[(r*2 + 0)*3 + l] + pd[(r*2 + 1)*3 + l] + bf3[l];
        out[(rb + r)*3 + l] = x[(rb + r)*3 + l] + 0.1f*delta;
    }
}

// ---------------------------------------------------------------------------
extern "C" void kernel_launch(void* const* d_in, const int* in_sizes, int n_in,
                              void* d_out, int out_size, void* d_ws, size_t ws_size,
                              hipStream_t stream)
{
    const float* x    = (const float*)d_in[0];
    const float* W1   = (const float*)d_in[1];
    const float* b1   = (const float*)d_in[2];
    const float* g1   = (const float*)d_in[3];
    const float* be1  = (const float*)d_in[4];
    const float* W2   = (const float*)d_in[5];
    const float* b2   = (const float*)d_in[6];
    const float* g2   = (const float*)d_in[7];
    const float* be2  = (const float*)d_in[8];
    const float* Ws1  = (const float*)d_in[9];
    const float* bs1  = (const float*)d_in[10];
    const float* Ws2  = (const float*)d_in[11];
    const float* bs2  = (const float*)d_in[12];
    const float* Wf1  = (const float*)d_in[13];
    const float* bf1  = (const float*)d_in[14];
    const float* gf1  = (const float*)d_in[15];
    const float* bef1 = (const float*)d_in[16];
    const float* Wf2  = (const float*)d_in[17];
    const float* bf2  = (const float*)d_in[18];
    const float* gf2  = (const float*)d_in[19];
    const float* bef2 = (const float*)d_in[20];
    const float* Wf3  = (const float*)d_in[21];
    const float* bf3  = (const float*)d_in[22];
    float* out = (float*)d_out;

    char* ws = (char*)d_ws;
    int*    idx   = (int*)   (ws + 0);             // 512 KB
    ushort* Wf1T  = (ushort*)(ws + (1u << 20));    // 96 KB
    ushort* Wf2T  = (ushort*)(ws + (1u << 20) + (512u << 10)); // 64 KB
    float*  P     = (float*) (ws + (2u  << 20));   // 4 MB   [BN][64] fp32
    ushort* Qb    = (ushort*)(ws + (6u  << 20));   // 2 MB   [BN][64] bf16

    k_pq<<<296, 256, 0, stream>>>(x, W1, b1, g1, be1, W2, Wf1, Wf2, P, Qb, Wf1T, Wf2T);
    k_knn<<<BB*64, 1024, 0, stream>>>(x, idx);
    k_fuse<<<BN/64, 256, 0, stream>>>(x, P, Qb, idx, Ws1, bs1, Ws2, bs2, b2, g2, be2,
                                      Wf1T, bf1, gf1, bef1, Wf2T, bf2, gf2, bef2,
                                      Wf3, bf3, out);
}

// Round 9
// 162.355 us; speedup vs baseline: 1.5621x; 1.0051x over previous
//
#include <hip/hip_runtime.h>
#include <hip/hip_bf16.h>
#include <math.h>

// Problem constants: B=8, N=2048, C_IN=3, D=64, K=8, LEVELS=3, H1=256, H2=128
#define BB   8
#define NN   2048
#define BN   16384   // B*N
#define KNB  8

__device__ __forceinline__ float leaky(float v){ return v > 0.f ? v : 0.2f*v; }

// RNE float->bf16 bits (finite inputs), matches __float2bfloat16 rounding
__device__ __forceinline__ ushort f2bf(float f){
    unsigned u = __float_as_uint(f);
    return (ushort)((u + 0x7FFFu + ((u >> 16) & 1u)) >> 16);
}
__device__ __forceinline__ float bf2f(ushort h){
    return __uint_as_float(((unsigned)h) << 16);
}

using bf16x8 = __attribute__((ext_vector_type(8))) short;
using f32x16 = __attribute__((ext_vector_type(16))) float;

// ---------------------------------------------------------------------------
// K1: fused feature-transform + PQ GEMM (fp32 math) + weight-transpose tail.
// blocks [0,256): tile 64 rows x 128 cols; P fp32 [BN][64], Q bf16 [BN][64].
// blocks [256,280): Wf1 [192][256] -> Wf1T bf16 [256][192]
// blocks [280,296): Wf2 [256][128] -> Wf2T bf16 [128][256]
// ---------------------------------------------------------------------------
__global__ __launch_bounds__(256) void k_pq(
    const float* __restrict__ x,
    const float* __restrict__ W1, const float* __restrict__ b1,
    const float* __restrict__ g1, const float* __restrict__ be1,
    const float* __restrict__ W2,
    const float* __restrict__ Wf1, const float* __restrict__ Wf2,
    float* __restrict__ P, ushort* __restrict__ Qb,
    ushort* __restrict__ Wf1T, ushort* __restrict__ Wf2T)
{
    int t = threadIdx.x;
    int bid = blockIdx.x;
    if (bid >= 256) {
        if (bid < 280) {
            int base = (bid - 256) * 2048 + t * 8;
            #pragma unroll
            for (int j = 0; j < 8; ++j) {
                int e = base + j;              // e < 49152
                int n = e / 192, k = e % 192;
                Wf1T[e] = f2bf(Wf1[k*256 + n]);
            }
        } else {
            int base = (bid - 280) * 2048 + t * 8;
            #pragma unroll
            for (int j = 0; j < 8; ++j) {
                int e = base + j;              // e < 32768
                int n = e / 256, k = e % 256;
                Wf2T[e] = f2bf(Wf2[k*128 + n]);
            }
        }
        return;
    }

    __shared__ float F_s[64*66];    // 16.9 KB
    __shared__ float W_s[32*132];   // 16.9 KB

    int rb = bid * 64;

    // feat: 4 groups of 64 threads (lane=d), 16 rows each
    {
        int d = t & 63, g = t >> 6;
        float w0 = W1[d], w1 = W1[64+d], w2 = W1[128+d];
        float bb = b1[d], gg = g1[d], ee = be1[d];
        #pragma unroll 4
        for (int i = 0; i < 16; ++i) {
            int r = g*16 + i;
            const float* xp = &x[(rb + r)*3];
            float f = xp[0]*w0 + xp[1]*w1 + xp[2]*w2 + bb;
            f = leaky(f*gg + ee);
            F_s[r*66 + d] = f;
        }
    }

    int tx = t & 15, ty = t >> 4;   // 8 cols x 4 rows micro-tile
    float acc[4][8];
    #pragma unroll
    for (int i = 0; i < 4; ++i)
        #pragma unroll
        for (int j = 0; j < 8; ++j) acc[i][j] = 0.f;

    for (int k0 = 0; k0 < 64; k0 += 32) {
        __syncthreads();
        // stage W' 32 x 128 : W'[k][c] = W2[k + 64*(c>=64)][c&63]
        #pragma unroll
        for (int it = 0; it < 2; ++it) {
            int i2 = t + it*256;                 // 0..511
            int k = i2 >> 4, c8 = (i2 & 15) * 8;
            const float* src = &W2[(k0 + k + (c8 >= 64 ? 64 : 0))*64 + (c8 & 63)];
            *(float4*)&W_s[k*132 + c8]     = *(const float4*)src;
            *(float4*)&W_s[k*132 + c8 + 4] = *(const float4*)(src + 4);
        }
        __syncthreads();
        #pragma unroll 4
        for (int kk = 0; kk < 32; ++kk) {
            float a[4];
            #pragma unroll
            for (int i = 0; i < 4; ++i) a[i] = F_s[(ty*4 + i)*66 + k0 + kk];
            float4 wA = *(const float4*)&W_s[kk*132 + tx*8];
            float4 wB = *(const float4*)&W_s[kk*132 + tx*8 + 4];
            #pragma unroll
            for (int i = 0; i < 4; ++i) {
                acc[i][0] = fmaf(a[i], wA.x, acc[i][0]);
                acc[i][1] = fmaf(a[i], wA.y, acc[i][1]);
                acc[i][2] = fmaf(a[i], wA.z, acc[i][2]);
                acc[i][3] = fmaf(a[i], wA.w, acc[i][3]);
                acc[i][4] = fmaf(a[i], wB.x, acc[i][4]);
                acc[i][5] = fmaf(a[i], wB.y, acc[i][5]);
                acc[i][6] = fmaf(a[i], wB.z, acc[i][6]);
                acc[i][7] = fmaf(a[i], wB.w, acc[i][7]);
            }
        }
    }

    #pragma unroll
    for (int i = 0; i < 4; ++i) {
        int r = rb + ty*4 + i;
        if (tx < 8) {        // cols 0..63 -> P (fp32)
            *(float4*)&P[r*64 + tx*8]     = make_float4(acc[i][0], acc[i][1], acc[i][2], acc[i][3]);
            *(float4*)&P[r*64 + tx*8 + 4] = make_float4(acc[i][4], acc[i][5], acc[i][6], acc[i][7]);
        } else {             // cols 64..127 -> Q (bf16)
            union { ushort u[8]; uint4 v; } pk;
            #pragma unroll
            for (int j = 0; j < 8; ++j) pk.u[j] = f2bf(acc[i][j]);
            *(uint4*)&Qb[r*64 + (tx - 8)*8] = pk.v;
        }
    }
}

// ---------------------------------------------------------------------------
// K2: exact KNN via value/index decomposition (output = SET of 8 nearest,
// order-free — downstream is an order-invariant max-pool; set == stable
// top-k set).
// Phase A: value-only top-8 scan (broadcast LDS reads), min/max CE networks.
// Phase A2: intra-wave merge + 4-level LDS tree -> v8[q] (exact 8th-smallest).
// Phase B: broadcast-layout rescan (same (q,seg) layout as phase A -> LDS
//   reads stay broadcast): d2 < v8 hits -> slots via per-query LDS atomics
//   (order-free, set semantics); ties at v8 buffered, cleanup picks lowest
//   indices.
// Block: 1024 thr = 32 queries x 32 segments x 64 candidates.
// ---------------------------------------------------------------------------
#define CEF(a, b) { float mn_ = fminf(a,b), mx_ = fmaxf(a,b); (a) = mn_; (b) = mx_; }

__global__ __launch_bounds__(1024, 8) void k_knn(const float* __restrict__ x, int* __restrict__ idxo)
{
    __shared__ __align__(16) char smem[51584];
    float4* sp    = (float4*)smem;                // [2048] 32 KB
    float*  mg    = (float*) (smem + 32768);      // [16][32][8] 16 KB
    float*  v8buf = (float*) (smem + 49152);      // [32]
    int*    eqbuf = (int*)   (smem + 49280);      // [32][16]
    int*    cnt   = (int*)   (smem + 51328);      // [32]
    int*    ecnt  = (int*)   (smem + 51456);      // [32]

    int t = threadIdx.x;
    int b = blockIdx.x >> 6;
    int qbase = (blockIdx.x & 63) * 32;
    int q = t & 31, seg = t >> 5;
    int w = t >> 6, lane = t & 63;

    for (int i = t; i < NN; i += 1024) {
        float a = x[(b*NN + i)*3 + 0];
        float c = x[(b*NN + i)*3 + 1];
        float e = x[(b*NN + i)*3 + 2];
        sp[i] = make_float4(a, c, e, a*a + c*c + e*e);
    }
    __syncthreads();

    // ---- Phase A: value-only top-8 over this (q,seg)'s 64 candidates ----
    float4 qv = sp[qbase + q];
    float R[8];
    #pragma unroll
    for (int j = 0; j < 8; ++j) R[j] = 1e30f;

    int m0 = seg * 64;
    #pragma unroll 2
    for (int g = 0; g < 8; ++g) {
        float S[8];
        #pragma unroll
        for (int jj = 0; jj < 8; ++jj) {
            int m = m0 + g*8 + jj;
            float4 v = sp[m];
            float s = qv.x*v.x; s = fmaf(qv.y, v.y, s); s = fmaf(qv.z, v.z, s);
            float d2 = fmaf(-2.f, s, qv.w + v.w);
            S[jj] = fmaxf(d2, 0.f);
        }
        // Batcher odd-even mergesort, 8 elems, 19 CEs (ascending)
        CEF(S[0],S[1]); CEF(S[2],S[3]); CEF(S[4],S[5]); CEF(S[6],S[7]);
        CEF(S[0],S[2]); CEF(S[1],S[3]); CEF(S[4],S[6]); CEF(S[5],S[7]);
        CEF(S[1],S[2]); CEF(S[5],S[6]);
        CEF(S[0],S[4]); CEF(S[1],S[5]); CEF(S[2],S[6]); CEF(S[3],S[7]);
        CEF(S[2],S[4]); CEF(S[3],S[5]);
        CEF(S[1],S[2]); CEF(S[3],S[4]); CEF(S[5],S[6]);
        // keep 8 smallest of R ∪ S
        #pragma unroll
        for (int j = 0; j < 8; ++j) R[j] = fminf(R[j], S[7-j]);
        CEF(R[0],R[4]); CEF(R[1],R[5]); CEF(R[2],R[6]); CEF(R[3],R[7]);
        CEF(R[0],R[2]); CEF(R[1],R[3]); CEF(R[4],R[6]); CEF(R[5],R[7]);
        CEF(R[0],R[1]); CEF(R[2],R[3]); CEF(R[4],R[5]); CEF(R[6],R[7]);
    }

    // ---- Phase A2a: intra-wave merge (seg 2w with seg 2w+1) ----
    {
        float Rp[8];
        #pragma unroll
        for (int j = 0; j < 8; ++j) Rp[j] = __shfl_xor(R[j], 32, 64);
        float C[8];
        #pragma unroll
        for (int j = 0; j < 8; ++j) C[j] = fminf(R[j], Rp[7-j]);
        CEF(C[0],C[4]); CEF(C[1],C[5]); CEF(C[2],C[6]); CEF(C[3],C[7]);
        CEF(C[0],C[2]); CEF(C[1],C[3]); CEF(C[4],C[6]); CEF(C[5],C[7]);
        CEF(C[0],C[1]); CEF(C[2],C[3]); CEF(C[4],C[5]); CEF(C[6],C[7]);
        if (lane < 32) {
            #pragma unroll
            for (int j = 0; j < 8; ++j) mg[(w*32 + lane)*8 + j] = C[j];
        }
    }

    // ---- Phase A2b: 4-level tree 16 -> 1, value-only ----
    #pragma unroll
    for (int lvl = 0; lvl < 4; ++lvl) {
        int P = 8 >> lvl;          // pairs per query
        int sh = 3 - lvl;
        bool active = (t < 32*P);
        float C[8];
        int qq = 0, p = 0;
        __syncthreads();
        if (active) {
            qq = t >> sh; p = t & (P - 1);
            float A[8], Bv[8];
            #pragma unroll
            for (int j = 0; j < 8; ++j) {
                A[j]  = mg[((2*p)*32 + qq)*8 + j];
                Bv[j] = mg[((2*p + 1)*32 + qq)*8 + j];
            }
            #pragma unroll
            for (int j = 0; j < 8; ++j) C[j] = fminf(A[j], Bv[7-j]);
            CEF(C[0],C[4]); CEF(C[1],C[5]); CEF(C[2],C[6]); CEF(C[3],C[7]);
            CEF(C[0],C[2]); CEF(C[1],C[3]); CEF(C[4],C[6]); CEF(C[5],C[7]);
            CEF(C[0],C[1]); CEF(C[2],C[3]); CEF(C[4],C[5]); CEF(C[6],C[7]);
        }
        __syncthreads();
        if (active) {
            if (P > 1) {
                #pragma unroll
                for (int j = 0; j < 8; ++j) mg[(p*32 + qq)*8 + j] = C[j];
            } else {
                v8buf[qq] = C[7];
            }
        }
    }
    if (t >= 32 && t < 64)  cnt[t - 32] = 0;
    if (t >= 64 && t < 96)  ecnt[t - 64] = 0;
    __syncthreads();

    // ---- Phase B: broadcast-layout index recovery ----
    {
        float v8 = v8buf[q];
        int obase = (b*NN + qbase + q)*KNB;
        #pragma unroll 4
        for (int jj = 0; jj < 64; ++jj) {
            int m = m0 + jj;
            float4 v = sp[m];                       // broadcast across 32 lanes
            float s = qv.x*v.x; s = fmaf(qv.y, v.y, s); s = fmaf(qv.z, v.z, s);
            float d2 = fmaf(-2.f, s, qv.w + v.w);
            d2 = fmaxf(d2, 0.f);
            if (d2 <= v8) {
                if (d2 < v8) {
                    int slot = atomicAdd(&cnt[q], 1);    // cLT <= 7 guaranteed
                    idxo[obase + slot] = b*NN + m;
                } else {
                    int slot = atomicAdd(&ecnt[q], 1);
                    if (slot < 16) eqbuf[q*16 + slot] = m;
                }
            }
        }
    }
    __syncthreads();

    // ---- cleanup: fill remaining slots with lowest-index ties at v8 ----
    if (t < 32) {
        int qq = t;
        int cLT = cnt[qq];                 // < 8 by definition of v8
        int ne = ecnt[qq]; if (ne > 16) ne = 16;
        int need = 8 - cLT;
        int obase = (b*NN + qbase + qq)*KNB;
        for (int k = 0; k < need; ++k) {
            int best = 0x7FFFFFFF, bi = -1;
            for (int i = 0; i < ne; ++i) {
                int v = eqbuf[qq*16 + i];
                if (v < best) { best = v; bi = i; }
            }
            if (bi >= 0) {
                eqbuf[qq*16 + bi] = 0x7FFFFFFF;
                idxo[obase + cLT + k] = b*NN + best;
            }
        }
    }
}

// ---------------------------------------------------------------------------
// K3: mega-fusion: suppressor(fw) + gather-max edge conv + multi(A) build
//     + h1 MFMA + h2 MFMA + Wf3 reduction + residual out.
// Block = 64 rows, 256 threads (4 waves). All intermediates stay in LDS.
// ---------------------------------------------------------------------------
__global__ __launch_bounds__(256) void k_fuse(
    const float* __restrict__ x,
    const float* __restrict__ P, const ushort* __restrict__ Qb,
    const int* __restrict__ idx,
    const float* __restrict__ Ws1, const float* __restrict__ bs1,
    const float* __restrict__ Ws2, const float* __restrict__ bs2,
    const float* __restrict__ b2, const float* __restrict__ g2,
    const float* __restrict__ be2,
    const ushort* __restrict__ Wf1T, const float* __restrict__ bf1,
    const float* __restrict__ gf1, const float* __restrict__ bef1,
    const ushort* __restrict__ Wf2T, const float* __restrict__ bf2,
    const float* __restrict__ gf2, const float* __restrict__ bef2,
    const float* __restrict__ Wf3, const float* __restrict__ bf3,
    float* __restrict__ out)
{
    __shared__ __align__(16) char smem[60928];
    ushort* A_s  = (ushort*)smem;             // [64][200]
    ushort* B_s  = (ushort*)(smem + 25600);   // [256][72]
    ushort* h1_s = (ushort*)smem;             // [64][264]
    ushort* B2_s = (ushort*)(smem + 40960);   // [128][72]
    float*  pd   = (float*) (smem + 59392);   // [64][2][3]

    int t = threadIdx.x, w = t >> 6, lane = t & 63;
    int rb = blockIdx.x * 64;

    // ---- phase A: fw + gather-max -> A_s (wave w: rows w*16..w*16+15) ----
    {
        float ws1a = Ws1[lane], ws1b = Ws1[64+lane], ws1c = Ws1[128+lane];
        float bs1v = bs1[lane];
        float ws2a = Ws2[lane*3+0], ws2b = Ws2[lane*3+1], ws2c = Ws2[lane*3+2];
        float bs20 = bs2[0], bs21 = bs2[1], bs22 = bs2[2];
        float g2v = g2[lane], be2v = be2[lane], b2v = b2[lane];
        for (int i = 0; i < 16; ++i) {
            int r = w*16 + i, p = rb + r;
            float x0 = x[p*3+0], x1 = x[p*3+1], x2 = x[p*3+2];
            float h = fmaxf(fmaf(x2, ws1c, fmaf(x1, ws1b, fmaf(x0, ws1a, bs1v))), 0.f);
            float s0 = h*ws2a, s1 = h*ws2b, s2 = h*ws2c;
            #pragma unroll
            for (int off = 32; off; off >>= 1) {
                s0 += __shfl_xor(s0, off, 64);
                s1 += __shfl_xor(s1, off, 64);
                s2 += __shfl_xor(s2, off, 64);
            }
            float fw0 = 1.f/(1.f + expf(-(s0 + bs20)));
            float fw1 = 1.f/(1.f + expf(-(s1 + bs21)));
            float fw2 = 1.f/(1.f + expf(-(s2 + bs22)));
            float Pv = P[p*64 + lane] + b2v;
            float mx = -1e30f;
            #pragma unroll
            for (int j = 0; j < KNB; ++j) {
                int nb = idx[p*KNB + j];
                float qv = bf2f(Qb[nb*64 + lane]);
                mx = fmaxf(mx, leaky((Pv + qv)*g2v + be2v));
            }
            A_s[r*200 + lane]       = f2bf(mx * fw0);
            A_s[r*200 + 64 + lane]  = f2bf(mx * fw1);
            A_s[r*200 + 128 + lane] = f2bf(mx * fw2);
        }
    }

    // ---- h1 = leaky((A @ Wf1 + bf1)*gf1 + bef1), N=256 full width ----
    int rg = w >> 1;                 // row-group 0/1
    int nh = (w & 1) * 128;          // h1 col-half
    int l31 = lane & 31, kb = (lane >> 5) * 8;
    int row = rg*32 + l31;

    f32x16 acc[4];
    #pragma unroll
    for (int n2 = 0; n2 < 4; ++n2)
        #pragma unroll
        for (int i = 0; i < 16; ++i) acc[n2][i] = 0.f;

    for (int k0 = 0; k0 < 192; k0 += 64) {
        __syncthreads();
        #pragma unroll
        for (int it = 0; it < 8; ++it) {
            int i = t + it*256;              // 0..2047
            int n = i >> 3, kq = (i & 7)*8;
            *(uint4*)&B_s[n*72 + kq] = *(const uint4*)&Wf1T[n*192 + k0 + kq];
        }
        __syncthreads();
        #pragma unroll
        for (int s = 0; s < 4; ++s) {
            bf16x8 a = *(const bf16x8*)&A_s[row*200 + k0 + s*16 + kb];
            #pragma unroll
            for (int n2 = 0; n2 < 4; ++n2) {
                bf16x8 b = *(const bf16x8*)&B_s[(nh + n2*32 + l31)*72 + s*16 + kb];
                acc[n2] = __builtin_amdgcn_mfma_f32_32x32x16_bf16(a, b, acc[n2], 0, 0, 0);
            }
        }
    }
    __syncthreads();   // A_s/B_s dead; safe to overwrite with h1_s

    #pragma unroll
    for (int n2 = 0; n2 < 4; ++n2) {
        int c = nh + n2*32 + l31;
        float bv = bf1[c], gv = gf1[c], ev = bef1[c];
        #pragma unroll
        for (int r16 = 0; r16 < 16; ++r16) {
            int rr = (r16 & 3) + 8*(r16 >> 2) + 4*(lane >> 5);
            float v = leaky((acc[n2][r16] + bv)*gv + ev);
            h1_s[(rg*32 + rr)*264 + c] = f2bf(v);
        }
    }

    // ---- h2 = leaky((h1 @ Wf2 + bf2)*gf2 + bef2), N=128; wave col-half 64 ----
    int ch = (w & 1) * 64;
    f32x16 acc2[2];
    #pragma unroll
    for (int n2 = 0; n2 < 2; ++n2)
        #pragma unroll
        for (int i = 0; i < 16; ++i) acc2[n2][i] = 0.f;

    for (int k0 = 0; k0 < 256; k0 += 64) {
        __syncthreads();
        #pragma unroll
        for (int it = 0; it < 4; ++it) {
            int i = t + it*256;              // 0..1023
            int n = i >> 3, kq = (i & 7)*8;
            *(uint4*)&B2_s[n*72 + kq] = *(const uint4*)&Wf2T[n*256 + k0 + kq];
        }
        __syncthreads();
        #pragma unroll
        for (int s = 0; s < 4; ++s) {
            bf16x8 a = *(const bf16x8*)&h1_s[row*264 + k0 + s*16 + kb];
            #pragma unroll
            for (int n2 = 0; n2 < 2; ++n2) {
                bf16x8 b = *(const bf16x8*)&B2_s[(ch + n2*32 + l31)*72 + s*16 + kb];
                acc2[n2] = __builtin_amdgcn_mfma_f32_32x32x16_bf16(a, b, acc2[n2], 0, 0, 0);
            }
        }
    }

    // ---- epilogue: per-row delta partials over this wave's 64 cols ----
    float bv[2], gv[2], ev[2], w3[2][3];
    #pragma unroll
    for (int n2 = 0; n2 < 2; ++n2) {
        int c = ch + n2*32 + l31;
        bv[n2] = bf2[c]; gv[n2] = gf2[c]; ev[n2] = bef2[c];
        #pragma unroll
        for (int l = 0; l < 3; ++l) w3[n2][l] = Wf3[c*3 + l];
    }
    __syncthreads();   // B2_s reads done; pd region free
    #pragma unroll
    for (int r16 = 0; r16 < 16; ++r16) {
        float d0 = 0.f, d1 = 0.f, d2 = 0.f;
        #pragma unroll
        for (int n2 = 0; n2 < 2; ++n2) {
            float v = leaky((acc2[n2][r16] + bv[n2])*gv[n2] + ev[n2]);
            d0 = fmaf(v, w3[n2][0], d0);
            d1 = fmaf(v, w3[n2][1], d1);
            d2 = fmaf(v, w3[n2][2], d2);
        }
        #pragma unroll
        for (int off = 16; off; off >>= 1) {   // reduce within 32-lane half
            d0 += __shfl_xor(d0, off, 64);
            d1 += __shfl_xor(d1, off, 64);
            d2 += __shfl_xor(d2, off, 64);
        }
        int rr = rg*32 + (r16 & 3) + 8*(r16 >> 2) + 4*(lane >> 5);
        if (l31 < 3) {
            float dl = (l31 == 0) ? d0 : (l31 == 1 ? d1 : d2);
            pd[(rr*2 + (w & 1))*3 + l31] = dl;
        }
    }
    __syncthreads();

    if (t < 192) {
        int r = t / 3, l = t - r*3;
        float delta = pd[(r*2 + 0)*3 + l] + pd[(r*2 + 1)*3 + l] + bf3[l];
        out[(rb + r)*3 + l] = x[(rb + r)*3 + l] + 0.1f*delta;
    }
}

// ---------------------------------------------------------------------------
extern "C" void kernel_launch(void* const* d_in, const int* in_sizes, int n_in,
                              void* d_out, int out_size, void* d_ws, size_t ws_size,
                              hipStream_t stream)
{
    const float* x    = (const float*)d_in[0];
    const float* W1   = (const float*)d_in[1];
    const float* b1   = (const float*)d_in[2];
    const float* g1   = (const float*)d_in[3];
    const float* be1  = (const float*)d_in[4];
    const float* W2   = (const float*)d_in[5];
    const float* b2   = (const float*)d_in[6];
    const float* g2   = (const float*)d_in[7];
    const float* be2  = (const float*)d_in[8];
    const float* Ws1  = (const float*)d_in[9];
    const float* bs1  = (const float*)d_in[10];
    const float* Ws2  = (const float*)d_in[11];
    const float* bs2  = (const float*)d_in[12];
    const float* Wf1  = (const float*)d_in[13];
    const float* bf1  = (const float*)d_in[14];
    const float* gf1  = (const float*)d_in[15];
    const float* bef1 = (const float*)d_in[16];
    const float* Wf2  = (const float*)d_in[17];
    const float* bf2  = (const float*)d_in[18];
    const float* gf2  = (const float*)d_in[19];
    const float* bef2 = (const float*)d_in[20];
    const float* Wf3  = (const float*)d_in[21];
    const float* bf3  = (const float*)d_in[22];
    float* out = (float*)d_out;

    char* ws = (char*)d_ws;
    int*    idx   = (int*)   (ws + 0);             // 512 KB
    ushort* Wf1T  = (ushort*)(ws + (1u << 20));    // 96 KB
    ushort* Wf2T  = (ushort*)(ws + (1u << 20) + (512u << 10)); // 64 KB
    float*  P     = (float*) (ws + (2u  << 20));   // 4 MB   [BN][64] fp32
    ushort* Qb    = (ushort*)(ws + (6u  << 20));   // 2 MB   [BN][64] bf16

    k_pq<<<296, 256, 0, stream>>>(x, W1, b1, g1, be1, W2, Wf1, Wf2, P, Qb, Wf1T, Wf2T);
    k_knn<<<BB*64, 1024, 0, stream>>>(x, idx);
    k_fuse<<<BN/64, 256, 0, stream>>>(x, P, Qb, idx, Ws1, bs1, Ws2, bs2, b2, g2, be2,
                                      Wf1T, bf1, gf1, bef1, Wf2T, bf2, gf2, bef2,
                                      Wf3, bf3, out);
}